// Round 7
// baseline (1100.885 us; speedup 1.0000x reference)
//
#include <hip/hip_runtime.h>

#define BB 32
#define SS 512
#define DD 256
#define HHH 512
#define NHH 8
#define HDD 64
#define PFF 2048
#define LLL 2
#define NN (BB*SS)      /* 16384 tokens */
#define NMAXX 15

typedef unsigned short u16;
typedef unsigned int u32;

typedef __attribute__((ext_vector_type(8))) __bf16 bf16x8;
typedef __attribute__((ext_vector_type(4))) float f32x4;

__device__ __forceinline__ float bf2f(u16 u) {
  union { u32 i; float f; } x; x.i = ((u32)u) << 16; return x.f;
}
__device__ __forceinline__ u16 f2bf(float f) {
  union { float f; u32 i; } x; x.f = f;
  u32 r = x.i + 0x7FFFu + ((x.i >> 16) & 1u);
  return (u16)(r >> 16);
}
// flag==1: inputs/outputs are bf16; flag==0: they are float32
__device__ __forceinline__ float ldf(const void* p, size_t i, int flag) {
  return flag ? bf2f(((const u16*)p)[i]) : ((const float*)p)[i];
}
__device__ __forceinline__ void stf(void* p, size_t i, int flag, float v) {
  if (flag) ((u16*)p)[i] = f2bf(v); else ((float*)p)[i] = v;
}
// async global->LDS, 16B per lane; LDS dest must be wave-uniform base + lane*16
__device__ __forceinline__ void gld16(const u16* g, u16* l) {
  __builtin_amdgcn_global_load_lds(
      (const __attribute__((address_space(1))) u32*)g,
      (__attribute__((address_space(3))) u32*)l, 16, 0, 0);
}

// ---------------- dtype probe: ln1_g[0] == 1.0 ----------------
__global__ void k_flag(const u32* __restrict__ ones, int* __restrict__ flag) {
  *flag = (ones[0] == 0x3F800000u) ? 0 : 1;
}

// ---------------- ALL weight transposes in ONE dispatch (6336 tiles, job ladder) ----------------
__global__ __launch_bounds__(256) void k_transpose_all(
    const void* __restrict__ socW, const void* __restrict__ projW,
    const void* __restrict__ Wq, const void* __restrict__ Wk,
    const void* __restrict__ Wv, const void* __restrict__ Wo,
    const void* __restrict__ W1, const void* __restrict__ W2,
    u16* __restrict__ socWT, u16* __restrict__ projWT, u16* __restrict__ WqkvT,
    u16* __restrict__ WoT, u16* __restrict__ W1T, u16* __restrict__ W2T,
    const int* __restrict__ flagp) {
  const size_t HH2 = (size_t)HHH * HHH, HP = (size_t)HHH * PFF;
  int bid = blockIdx.x;
  const void* in; size_t ioff; u16* out; int R, C;
  if (bid < 64)       { in = socW;  ioff = 0; out = socWT;  R = DD; C = DD;  }
  else if (bid < 192) { bid -= 64; in = projW; ioff = 0; out = projWT; R = DD; C = HHH; }
  else {
    int r = bid - 192;
    int l = r / 3072; r -= l * 3072;
    size_t oHH = (size_t)l * HH2, oHP = (size_t)l * HP;
    if (r < 256)       { in = Wq; ioff = oHH; out = WqkvT + (size_t)l*3*HH2;          R = HHH; C = HHH; bid = r; }
    else if (r < 512)  { in = Wk; ioff = oHH; out = WqkvT + (size_t)l*3*HH2 + HH2;    R = HHH; C = HHH; bid = r - 256; }
    else if (r < 768)  { in = Wv; ioff = oHH; out = WqkvT + (size_t)l*3*HH2 + 2*HH2;  R = HHH; C = HHH; bid = r - 512; }
    else if (r < 1024) { in = Wo; ioff = oHH; out = WoT + oHH;                        R = HHH; C = HHH; bid = r - 768; }
    else if (r < 2048) { in = W1; ioff = oHP; out = W1T + oHP;                        R = HHH; C = PFF; bid = r - 1024; }
    else               { in = W2; ioff = oHP; out = W2T + oHP;                        R = PFF; C = HHH; bid = r - 2048; }
  }
  int ntx = C >> 5;
  int c0 = (bid % ntx) * 32, r0 = (bid / ntx) * 32;
  __shared__ u16 tile[32][33];
  int flag = *flagp;
  int tx = threadIdx.x, ty = threadIdx.y;  // 32 x 8
  #pragma unroll
  for (int i = 0; i < 4; ++i)
    tile[ty + i*8][tx] = f2bf(ldf(in, ioff + (size_t)(r0 + ty + i*8) * C + c0 + tx, flag));
  __syncthreads();
  #pragma unroll
  for (int i = 0; i < 4; ++i) out[(size_t)(c0 + ty + i*8) * R + r0 + tx] = tile[tx][ty + i*8];
}

// ---------------- pack all biases to bf16 ----------------
// layout: [projb 512][per-layer: bq,bk,bv (1536) | b1 (2048) | bo (512) | b2 (512)]
__global__ __launch_bounds__(256) void k_packb(const void* __restrict__ projb,
    const void* __restrict__ bq, const void* __restrict__ bk, const void* __restrict__ bv,
    const void* __restrict__ b1, const void* __restrict__ bo, const void* __restrict__ b2,
    u16* __restrict__ out, const int* __restrict__ flagp) {
  int flag = *flagp;
  int i = blockIdx.x * 256 + threadIdx.x;
  int tot = 512 + LLL * 4608;
  if (i >= tot) return;
  float v;
  if (i < 512) v = ldf(projb, i, flag);
  else {
    int j = i - 512, l = j / 4608, r = j % 4608;
    if      (r < 512)  v = ldf(bq, (size_t)l * HHH + r, flag);
    else if (r < 1024) v = ldf(bk, (size_t)l * HHH + r - 512, flag);
    else if (r < 1536) v = ldf(bv, (size_t)l * HHH + r - 1024, flag);
    else if (r < 3584) v = ldf(b1, (size_t)l * PFF + r - 1536, flag);
    else if (r < 4096) v = ldf(bo, (size_t)l * HHH + r - 3584, flag);
    else               v = ldf(b2, (size_t)l * HHH + r - 4096, flag);
  }
  out[i] = f2bf(v);
}

// ---------------- PE + time-bias table: pet[s][d] = PE(s,d) + tB[d] ----------------
__global__ __launch_bounds__(256) void k_pe(const void* __restrict__ tB,
    u16* __restrict__ pet, const int* __restrict__ flagp) {
  int flag = *flagp;
  int s = blockIdx.x, d = threadIdx.x;
  int i2 = d & ~1;
  float freq = expf(-0.035977892078031968f * (float)i2);
  float ang = (float)s * freq;
  float v = ((d & 1) ? cosf(ang) : sinf(ang)) + ldf(tB, d, flag);
  pet[(size_t)s * DD + d] = f2bf(v);
}

// ---------------- embedding + PE table + time encoding (no trig) ----------------
__global__ __launch_bounds__(256) void k_embed(const int* __restrict__ src,
    const void* __restrict__ tiv, const void* __restrict__ emb,
    const void* __restrict__ tW, const u16* __restrict__ pet,
    u16* __restrict__ X, const int* __restrict__ flagp) {
  int flag = *flagp;
  int n = blockIdx.x, d = threadIdx.x;
  int s = n & (SS - 1);
  int tok = src[n];
  float v = ldf(emb, (size_t)tok * DD + d, flag);
  v += bf2f(pet[(size_t)s * DD + d]);
  float t = ldf(tiv, n, flag);
  v += t * ldf(tW, d, flag);
  X[(size_t)n * DD + d] = f2bf(v);
}

// ---------------- neighbor mean aggregation ----------------
__global__ __launch_bounds__(256) void k_agg(const int* __restrict__ nidx,
    const int* __restrict__ ncnt, const u16* __restrict__ X, u16* __restrict__ AGG) {
  int n = blockIdx.x, d = threadIdx.x;
  int cnt = ncnt[n];
  float s = 0.f;
  for (int j = 0; j < cnt; ++j) {
    int m = nidx[n * NMAXX + j];
    s += bf2f(X[(size_t)m * DD + d]);
  }
  float div = (float)(cnt > 0 ? cnt : 1);
  AGG[(size_t)n * DD + d] = f2bf(s / div);
}

// ---------------- m97-style bf16 MFMA GEMM (kept for soc, N=256) ----------------
__global__ __launch_bounds__(256) void k_gemm128(const u16* __restrict__ A,
    const u16* __restrict__ BT, const void* __restrict__ bias, int boff,
    const u16* __restrict__ res, u16* __restrict__ C, int N, int K, int relu,
    const int* __restrict__ flagp) {
  __shared__ __align__(16) u16 As[128 * 32];
  __shared__ __align__(16) u16 Bs[128 * 32];
  int n0 = blockIdx.x * 128, m0 = blockIdx.y * 128;
  int t = threadIdx.x;
  int lane = t & 63, w = t >> 6;
  int wm = (w >> 1) * 64, wn = (w & 1) * 64;
  int fr = lane & 15, fq = lane >> 4;
  int srow = t >> 2, sseg = t & 3;

  f32x4 acc[4][4];
  #pragma unroll
  for (int i = 0; i < 4; ++i)
    #pragma unroll
    for (int j = 0; j < 4; ++j) acc[i][j] = (f32x4){0.f, 0.f, 0.f, 0.f};

  const u16* ga = A  + (size_t)(m0 + srow) * K + sseg * 8;
  const u16* gb = BT + (size_t)(n0 + srow) * K + sseg * 8;
  u16* lA = As + srow * 32 + sseg * 8;
  u16* lB = Bs + srow * 32 + sseg * 8;
  const size_t rstride = (size_t)64 * K;

  for (int k0 = 0; k0 < K; k0 += 32) {
    gld16(ga + k0, lA);
    gld16(ga + k0 + rstride, lA + 64 * 32);
    gld16(gb + k0, lB);
    gld16(gb + k0 + rstride, lB + 64 * 32);
    __syncthreads();
    bf16x8 af[4], bf[4];
    #pragma unroll
    for (int i = 0; i < 4; ++i) af[i] = *(const bf16x8*)&As[(wm + i * 16 + fr) * 32 + fq * 8];
    #pragma unroll
    for (int j = 0; j < 4; ++j) bf[j] = *(const bf16x8*)&Bs[(wn + j * 16 + fr) * 32 + fq * 8];
    #pragma unroll
    for (int i = 0; i < 4; ++i)
      #pragma unroll
      for (int j = 0; j < 4; ++j)
        acc[i][j] = __builtin_amdgcn_mfma_f32_16x16x32_bf16(af[i], bf[j], acc[i][j], 0, 0, 0);
    __syncthreads();
  }

  int flag = *flagp;
  #pragma unroll
  for (int j = 0; j < 4; ++j) {
    int col = n0 + wn + j * 16 + fr;
    float bv = bias ? ldf(bias, boff + col, flag) : 0.f;
    #pragma unroll
    for (int i = 0; i < 4; ++i) {
      #pragma unroll
      for (int c = 0; c < 4; ++c) {
        int row = m0 + wm + i * 16 + fq * 4 + c;
        float v = acc[i][j][c] + bv;
        if (res) v += bf2f(res[(size_t)row * N + col]);
        if (relu) v = fmaxf(v, 0.f);
        C[(size_t)row * N + col] = f2bf(v);
      }
    }
  }
}

// ---------------- pipelined 256-row-tile GEMM: BM=256, BN=64*NBF, BK=32 ----------------
template<int NBF>
__global__ __launch_bounds__(512, 2) void k_gemm256(const u16* __restrict__ A,
    const u16* __restrict__ BT, const u16* __restrict__ bias,
    u16* __restrict__ C, int N, int K, int relu, int nbx) {
  constexpr int AG = 1024;
  constexpr int BG = NBF * 256;
  constexpr int STRIDE = (AG + BG) * 8;
  constexpr int LPT = 2 + BG / 512;
  __shared__ __align__(16) u16 S[3 * STRIDE];

  int nwg = gridDim.x;
  int id = blockIdx.x;
  int wg = ((nwg & 7) == 0) ? ((id & 7) * (nwg >> 3) + (id >> 3)) : id;
  int bx = wg % nbx, by = wg / nbx;
  int m0 = by * 256, n0 = bx * (64 * NBF);

  int t = threadIdx.x;
  int w = t >> 6, lane = t & 63;
  int fr = lane & 15, fq = lane >> 4;
  int wm = (w >> 2) * 128, wn = (w & 3) * (16 * NBF);
  int gsw8 = (fq ^ (fr & 3) ^ ((fr >> 2) & 3)) * 8;

  int arow = t >> 2, aseg = t & 3;
  int asw = aseg ^ (arow & 3) ^ ((arow >> 2) & 3);
  const u16* gA  = A  + (size_t)(m0 + arow) * K + asw * 8;
  const u16* gA2 = gA + (size_t)128 * K;
  const u16* gB  = BT + (size_t)(n0 + arow) * K + asw * 8;
  const u16* gB2 = gB + (size_t)128 * K;

  f32x4 acc[8][NBF];
  #pragma unroll
  for (int i = 0; i < 8; ++i)
    #pragma unroll
    for (int j = 0; j < NBF; ++j) acc[i][j] = (f32x4){0.f, 0.f, 0.f, 0.f};

  int NT = K >> 5;

  #pragma unroll
  for (int p = 0; p < 2; ++p) {
    gld16(gA  + p * 32, S + p * STRIDE + t * 8);
    gld16(gA2 + p * 32, S + p * STRIDE + (t + 512) * 8);
    gld16(gB  + p * 32, S + p * STRIDE + AG * 8 + t * 8);
    if constexpr (NBF == 4)
      gld16(gB2 + p * 32, S + p * STRIDE + AG * 8 + (t + 512) * 8);
  }
  asm volatile("s_waitcnt vmcnt(%0)" :: "n"(LPT) : "memory");
  __builtin_amdgcn_s_barrier();
  __builtin_amdgcn_sched_barrier(0);

  for (int T = 0; T < NT; ++T) {
    const u16* Sa = S + (T % 3) * STRIDE;
    const u16* Sb = Sa + AG * 8;
    u16* Sn = S + ((T + 2) % 3) * STRIDE;
    int kn = (T + 2) * 32;
    bool st = (T + 2) < NT;

    bf16x8 af[4], bf[NBF];
    #pragma unroll
    for (int i = 0; i < 4; ++i) af[i] = *(const bf16x8*)&Sa[(wm + i * 16 + fr) * 32 + gsw8];
    #pragma unroll
    for (int j = 0; j < NBF; ++j) bf[j] = *(const bf16x8*)&Sb[(wn + j * 16 + fr) * 32 + gsw8];
    if (st) {
      gld16(gA  + kn, Sn + t * 8);
      gld16(gA2 + kn, Sn + (t + 512) * 8);
    }
    __builtin_amdgcn_s_setprio(1);
    #pragma unroll
    for (int i = 0; i < 4; ++i)
      #pragma unroll
      for (int j = 0; j < NBF; ++j)
        acc[i][j] = __builtin_amdgcn_mfma_f32_16x16x32_bf16(af[i], bf[j], acc[i][j], 0, 0, 0);
    __builtin_amdgcn_s_setprio(0);

    bf16x8 ag[4];
    #pragma unroll
    for (int i = 0; i < 4; ++i) ag[i] = *(const bf16x8*)&Sa[(wm + 64 + i * 16 + fr) * 32 + gsw8];
    if (st) {
      gld16(gB + kn, Sn + AG * 8 + t * 8);
      if constexpr (NBF == 4)
        gld16(gB2 + kn, Sn + AG * 8 + (t + 512) * 8);
    }
    __builtin_amdgcn_s_setprio(1);
    #pragma unroll
    for (int i = 0; i < 4; ++i)
      #pragma unroll
      for (int j = 0; j < NBF; ++j)
        acc[4 + i][j] = __builtin_amdgcn_mfma_f32_16x16x32_bf16(ag[i], bf[j], acc[4 + i][j], 0, 0, 0);
    __builtin_amdgcn_s_setprio(0);

    if (st) { asm volatile("s_waitcnt vmcnt(%0) lgkmcnt(0)" :: "n"(LPT) : "memory"); }
    else    { asm volatile("s_waitcnt vmcnt(0) lgkmcnt(0)" ::: "memory"); }
    __builtin_amdgcn_s_barrier();
    __builtin_amdgcn_sched_barrier(0);
  }

  // epilogue: row-major store order for write combining
  float bvj[NBF];
  #pragma unroll
  for (int j = 0; j < NBF; ++j) bvj[j] = bf2f(bias[n0 + wn + j * 16 + fr]);
  #pragma unroll
  for (int i = 0; i < 8; ++i) {
    #pragma unroll
    for (int c = 0; c < 4; ++c) {
      size_t rowb = (size_t)(m0 + wm + i * 16 + fq * 4 + c) * N;
      #pragma unroll
      for (int j = 0; j < NBF; ++j) {
        int col = n0 + wn + j * 16 + fr;
        float v = acc[i][j][c] + bvj[j];
        if (relu) v = fmaxf(v, 0.f);
        C[rowb + col] = f2bf(v);
      }
    }
  }
}

// ---------------- soc LayerNorm(D=256) + relu + select + x += 0.2*soc ----------------
__global__ __launch_bounds__(256) void k_ln_soc(const u16* __restrict__ socp,
    const u16* __restrict__ X, const void* __restrict__ g, const void* __restrict__ beta,
    const int* __restrict__ ncnt, const int* __restrict__ src,
    u16* __restrict__ X2, void* __restrict__ dout, const int* __restrict__ flagp) {
  __shared__ float sred[4];
  int flag = *flagp;
  int n = blockIdx.x, t = threadIdx.x;
  size_t base = (size_t)n * DD;
  float v = bf2f(socp[base + t]);
  float s = v;
  #pragma unroll
  for (int o = 32; o; o >>= 1) s += __shfl_xor(s, o, 64);
  if ((t & 63) == 0) sred[t >> 6] = s;
  __syncthreads();
  float mean = (sred[0] + sred[1] + sred[2] + sred[3]) * (1.f / DD);
  float dv = v - mean;
  float q = dv * dv;
  #pragma unroll
  for (int o = 32; o; o >>= 1) q += __shfl_xor(q, o, 64);
  __syncthreads();
  if ((t & 63) == 0) sred[t >> 6] = q;
  __syncthreads();
  float var = (sred[0] + sred[1] + sred[2] + sred[3]) * (1.f / DD);
  float rs = rsqrtf(var + 1e-5f);
  float soc = fmaxf(dv * rs * ldf(g, t, flag) + ldf(beta, t, flag), 0.f);
  float xv = bf2f(X[base + t]);
  if (ncnt[n] <= 0) soc = xv;
  if (src[n] == 0)  soc = 0.f;
  float ov = xv + 0.2f * soc;
  X2[base + t] = f2bf(ov);
  stf(dout, (size_t)NN * HHH + base + t, flag, ov);
}

// ---------------- LayerNorm(H=512) of (a+b); out bf16, or dout (output dtype) ----------------
__global__ __launch_bounds__(256) void k_ln_add(const u16* __restrict__ a,
    const u16* __restrict__ b, const void* __restrict__ g, int goff,
    const void* __restrict__ bb, int boff, u16* __restrict__ out,
    void* __restrict__ dout, const int* __restrict__ flagp) {
  __shared__ float sred[4];
  int flag = *flagp;
  int row = blockIdx.x, t = threadIdx.x;
  size_t base = (size_t)row * HHH;
  float v0 = bf2f(a[base + t])       + bf2f(b[base + t]);
  float v1 = bf2f(a[base + 256 + t]) + bf2f(b[base + 256 + t]);
  float s = v0 + v1;
  #pragma unroll
  for (int o = 32; o; o >>= 1) s += __shfl_xor(s, o, 64);
  if ((t & 63) == 0) sred[t >> 6] = s;
  __syncthreads();
  float mean = (sred[0] + sred[1] + sred[2] + sred[3]) * (1.f / HHH);
  float d0 = v0 - mean, d1 = v1 - mean;
  float q = d0 * d0 + d1 * d1;
  #pragma unroll
  for (int o = 32; o; o >>= 1) q += __shfl_xor(q, o, 64);
  __syncthreads();
  if ((t & 63) == 0) sred[t >> 6] = q;
  __syncthreads();
  float var = (sred[0] + sred[1] + sred[2] + sred[3]) * (1.f / HHH);
  float rs = rsqrtf(var + 1e-5f);
  float o0 = d0 * rs * ldf(g, goff + t, flag)       + ldf(bb, boff + t, flag);
  float o1 = d1 * rs * ldf(g, goff + 256 + t, flag) + ldf(bb, boff + 256 + t, flag);
  if (dout) {
    stf(dout, base + t, flag, o0);
    stf(dout, base + 256 + t, flag, o1);
  } else {
    out[base + t]       = f2bf(o0);
    out[base + 256 + t] = f2bf(o1);
  }
}

// ---------------- MFMA attention: one block per (head, batch); Q/K/V strided (ld) ----------------
// Swapped QK^T: sacc[t] = mfma(kf, qf) -> lane (fq,fr) holds S[key=16t+4fq+c][q=qb+fr].
// Softmax fully per-lane (128 vals) + 2 shfl_xor across fq groups. Mask is additive bias.
// P -> bf16 via v_cvt_pk_bf16_f32 pairs, ds_write_b64 into Ps[q=fr][key] -- which IS the
// pa A-frag layout, so PV and the O-write are byte-identical to the R4-measured code.
__global__ __launch_bounds__(512, 2) void k_attn_mfma(const u16* __restrict__ Q,
    const u16* __restrict__ Kb, const u16* __restrict__ Vb, int ld,
    const int* __restrict__ src, u16* __restrict__ O) {
  __shared__ __align__(16) u16 Ks[512 * 64];
  __shared__ __align__(16) u16 VTs[64 * 512];
  __shared__ __align__(16) u16 Ps[128 * 72];
  __shared__ __align__(16) float maskv[512];
  int h = blockIdx.x, b = blockIdx.y;
  int t = threadIdx.x;
  int w = t >> 6, lane = t & 63;
  int fr = lane & 15, fq = lane >> 4;

  maskv[t] = (src[b * SS + t] != 0) ? 0.f : -8.0e10f;   // additive bias

  #pragma unroll
  for (int i = 0; i < 8; ++i) {
    int off = t + i * 512;
    int row = off >> 3;
    int gs  = (off & 7) ^ (row & 7);
    gld16(Kb + (size_t)(b * SS + row) * ld + h * HDD + gs * 8, Ks + (size_t)off * 8);
  }
  {
    const u16* vsrc = Vb + (size_t)(b * SS + t) * ld + h * HDD;
    int ghi = (t >> 3) & ~7, glo = (t >> 3) & 7, kw = t & 7;
    #pragma unroll
    for (int i = 0; i < 8; ++i) {
      uint4 raw = *(const uint4*)(vsrc + i * 8);
      u16 e[8]; *(uint4*)e = raw;
      #pragma unroll
      for (int jj = 0; jj < 8; ++jj) {
        int d = i * 8 + jj;
        VTs[(size_t)d * 512 + (size_t)((ghi | (glo ^ (d & 7))) * 8 + kw)] = e[jj];
      }
    }
  }
  __syncthreads();

  for (int chunk = 0; chunk < 4; ++chunk) {
    int qb = chunk * 128 + w * 16;
    bf16x8 qf[2];
    #pragma unroll
    for (int kc = 0; kc < 2; ++kc)
      qf[kc] = *(const bf16x8*)&Q[(size_t)(b * SS + qb + fr) * ld + h * HDD + kc * 32 + fq * 8];

    f32x4 sacc[32];
    #pragma unroll
    for (int j = 0; j < 32; ++j) sacc[j] = (f32x4){0.f, 0.f, 0.f, 0.f};

    // QK^T swapped: A = K rows (key), B = Q rows (q) -> C[key][q], q = fr lane-local
    #pragma unroll
    for (int kt = 0; kt < 32; ++kt) {
      int row = kt * 16 + fr;
      #pragma unroll
      for (int kc = 0; kc < 2; ++kc) {
        bf16x8 kf = *(const bf16x8*)&Ks[(size_t)row * 64 +
            (size_t)(((kc * 4 + fq) ^ (fr & 7)) * 8)];
        sacc[kt] = __builtin_amdgcn_mfma_f32_16x16x32_bf16(kf, qf[kc], sacc[kt], 0, 0, 0);
      }
    }

    // additive mask bias: key = 16t + 4fq + c
    #pragma unroll
    for (int j = 0; j < 32; ++j) {
      f32x4 av = *(const f32x4*)&maskv[j * 16 + fq * 4];
      #pragma unroll
      for (int c = 0; c < 4; ++c) sacc[j][c] += av[c];
    }

    // per-lane softmax over 128 keys + 2 shfl_xor across fq groups
    float m0 = -3.0e38f, m1 = -3.0e38f, m2 = -3.0e38f, m3 = -3.0e38f;
    #pragma unroll
    for (int j = 0; j < 32; ++j) {
      m0 = fmaxf(m0, sacc[j][0]); m1 = fmaxf(m1, sacc[j][1]);
      m2 = fmaxf(m2, sacc[j][2]); m3 = fmaxf(m3, sacc[j][3]);
    }
    float m = fmaxf(fmaxf(m0, m1), fmaxf(m2, m3));
    m = fmaxf(m, __shfl_xor(m, 16, 64));
    m = fmaxf(m, __shfl_xor(m, 32, 64));
    float ms = m * 0.125f;
    float s0 = 0.f, s1 = 0.f, s2 = 0.f, s3 = 0.f;
    #pragma unroll
    for (int j = 0; j < 32; ++j) {
      float e0 = __expf(fmaf(sacc[j][0], 0.125f, -ms));
      float e1 = __expf(fmaf(sacc[j][1], 0.125f, -ms));
      float e2 = __expf(fmaf(sacc[j][2], 0.125f, -ms));
      float e3 = __expf(fmaf(sacc[j][3], 0.125f, -ms));
      sacc[j][0] = e0; sacc[j][1] = e1; sacc[j][2] = e2; sacc[j][3] = e3;
      s0 += e0; s1 += e1; s2 += e2; s3 += e3;
    }
    float s = (s0 + s1) + (s2 + s3);
    s += __shfl_xor(s, 16, 64);
    s += __shfl_xor(s, 32, 64);
    float inv = 1.f / s;                       // for q = qb + fr (uniform across fq)
    float invc[4];
    #pragma unroll
    for (int c = 0; c < 4; ++c) invc[c] = __shfl(inv, fq * 4 + c, 64);

    f32x4 oacc[4];
    #pragma unroll
    for (int n = 0; n < 4; ++n) oacc[n] = (f32x4){0.f, 0.f, 0.f, 0.f};

    // PV: unchanged structure. Ps write: per 16-key tile, 2 cvt_pk + 1 ds_write_b64
    // into Ps[q = w*16+fr][within-seg key = 16tt + 4fq]  (pa layout).
    #pragma unroll
    for (int seg = 0; seg < 8; ++seg) {
      #pragma unroll
      for (int tt = 0; tt < 4; ++tt) {
        int j = seg * 4 + tt;
        u32 lo, hi;
        asm("v_cvt_pk_bf16_f32 %0, %1, %2" : "=v"(lo) : "v"(sacc[j][0]), "v"(sacc[j][1]));
        asm("v_cvt_pk_bf16_f32 %0, %1, %2" : "=v"(hi) : "v"(sacc[j][2]), "v"(sacc[j][3]));
        uint2 pk; pk.x = lo; pk.y = hi;
        *(uint2*)&Ps[(size_t)(w * 16 + fr) * 72 + tt * 16 + fq * 4] = pk;
      }
      #pragma unroll
      for (int kc = 0; kc < 2; ++kc) {
        bf16x8 pa = *(const bf16x8*)&Ps[(size_t)(w * 16 + fr) * 72 + kc * 32 + fq * 8];
        #pragma unroll
        for (int nt = 0; nt < 4; ++nt) {
          bf16x8 bv = *(const bf16x8*)&VTs[(size_t)(nt * 16 + fr) * 512 +
              (size_t)((seg * 8 + ((kc * 4 + fq) ^ (fr & 7))) * 8)];
          oacc[nt] = __builtin_amdgcn_mfma_f32_16x16x32_bf16(pa, bv, oacc[nt], 0, 0, 0);
        }
      }
    }

    // O-write: unchanged pattern; normalize by invc (P stored unnormalized)
    #pragma unroll
    for (int nt = 0; nt < 4; ++nt)
      #pragma unroll
      for (int c = 0; c < 4; ++c)
        O[(size_t)(b * SS + qb + fq * 4 + c) * HHH + h * HDD + nt * 16 + fr] =
            f2bf(oacc[nt][c] * invc[c]);
  }
}

extern "C" void kernel_launch(void* const* d_in, const int* in_sizes, int n_in,
                              void* d_out, int out_size, void* d_ws, size_t ws_size,
                              hipStream_t stream) {
  (void)in_sizes; (void)n_in; (void)out_size;
  const int* src    = (const int*)d_in[0];
  const int* nidx   = (const int*)d_in[2];
  const int* ncnt   = (const int*)d_in[3];
  const void* tiv   = d_in[4];
  const void* emb   = d_in[5];
  const void* tW    = d_in[6];
  const void* tB    = d_in[7];
  const void* socW  = d_in[8];
  const void* socb  = d_in[9];
  const void* socg  = d_in[10];
  const void* socbe = d_in[11];
  const void* projW = d_in[12];
  const void* projb = d_in[13];
  const void* Wq    = d_in[14];
  const void* bq    = d_in[15];
  const void* Wk    = d_in[16];
  const void* bk    = d_in[17];
  const void* Wv    = d_in[18];
  const void* bv    = d_in[19];
  const void* Wo    = d_in[20];
  const void* bo    = d_in[21];
  const void* ln1g  = d_in[22];
  const void* ln1b  = d_in[23];
  const void* W1    = d_in[24];
  const void* b1    = d_in[25];
  const void* W2    = d_in[26];
  const void* b2    = d_in[27];
  const void* ln2g  = d_in[28];
  const void* ln2b  = d_in[29];

  const size_t NHS = (size_t)NN * HHH;
  const size_t QKV3 = (size_t)3 * HHH * HHH;
  u16* ws = (u16*)d_ws;
  u16* socWT  = ws;
  u16* projWT = socWT + (size_t)DD * DD;
  u16* WqkvT  = projWT + (size_t)DD * HHH;
  u16* WoT    = WqkvT + (size_t)LLL * QKV3;
  u16* W1T    = WoT + (size_t)LLL * HHH * HHH;
  u16* W2T    = W1T + (size_t)LLL * HHH * PFF;
  u16* Hb     = W2T + (size_t)LLL * HHH * PFF;
  u16* P1     = Hb + NHS;
  u16* P2     = P1 + NHS;
  u16* P3     = P2 + NHS;
  int* flagp  = (int*)(P3 + NHS);
  u16* packb  = (u16*)(flagp + 4);
  u16* pet    = packb + 16384;                    // PE table [512,256]
  u16* FFMf   = pet + (size_t)SS * DD;            // full FFM [16384,2048] (if ws allows)
  size_t need_full = (size_t)(FFMf - ws + (size_t)NN * PFF) * 2;
  int fullff = (ws_size >= need_full);

  u16* X    = P1;
  u16* AGG  = P2;
  u16* SOCP = P3;
  u16* X2   = P2;
  u16* Ob   = (u16*)d_out;
  u16* FFMc = P2;    // chunked fallback: [8192,2048] spans P2+P3

  k_flag<<<1, 1, 0, stream>>>((const u32*)ln1g, flagp);

  dim3 tb(32, 8);
  k_transpose_all<<<dim3(192 + LLL * 3072), tb, 0, stream>>>(
      socW, projW, Wq, Wk, Wv, Wo, W1, W2,
      socWT, projWT, WqkvT, WoT, W1T, W2T, flagp);
  k_packb<<<dim3((512 + LLL * 4608 + 255) / 256), 256, 0, stream>>>(
      projb, bq, bk, bv, b1, bo, b2, packb, flagp);
  k_pe<<<SS, 256, 0, stream>>>(tB, pet, flagp);

  k_embed<<<NN, 256, 0, stream>>>(src, tiv, emb, tW, pet, X, flagp);
  k_agg<<<NN, 256, 0, stream>>>(nidx, ncnt, X, AGG);
  k_gemm128<<<dim3(DD / 128, NN / 128), 256, 0, stream>>>(AGG, socWT, socb, 0, X, SOCP, DD, DD, 0, flagp);
  k_ln_soc<<<NN, 256, 0, stream>>>(SOCP, X, socg, socbe, ncnt, src, X2, d_out, flagp);
  // proj: [16384,256] @ [256,512] -> Hb
  k_gemm256<2><<<dim3(256), 512, 0, stream>>>(X2, projWT, packb, Hb, HHH, DD, 0, 4);

  for (int l = 0; l < LLL; ++l) {
    size_t oHH = (size_t)l * HHH * HHH, oHP = (size_t)l * HHH * PFF;
    u16* lb = packb + 512 + (size_t)l * 4608;
    // fused QKV: [16384,512] @ [512,1536] -> P1 (row stride 1536, spans P1..P3)
    k_gemm256<4><<<dim3(384), 512, 0, stream>>>(Hb, WqkvT + (size_t)l * QKV3, lb, P1, 1536, HHH, 0, 6);
    k_attn_mfma<<<dim3(NHH, BB), 512, 0, stream>>>(P1, P1 + HHH, P1 + 2 * HHH, 3 * HHH, src, Ob);
    // Wo: [16384,512] @ [512,512] -> P1
    k_gemm256<2><<<dim3(256), 512, 0, stream>>>(Ob, WoT + oHH, lb + 3584, P1, HHH, HHH, 0, 4);
    k_ln_add<<<NN, 256, 0, stream>>>(Hb, P1, ln1g, l * HHH, ln1b, l * HHH, Hb, nullptr, flagp);
    if (fullff) {
      // FF1: [16384,512]@[512,2048] -> FFMf (grid 512); FF2: -> P1 (grid 256, FULL occupancy)
      k_gemm256<4><<<dim3(512), 512, 0, stream>>>(Hb, W1T + oHP, lb + 1536, FFMf, PFF, HHH, 1, 8);
      k_gemm256<2><<<dim3(256), 512, 0, stream>>>(FFMf, W2T + oHP, lb + 4096, P1, HHH, PFF, 0, 4);
    } else {
      for (int c = 0; c < 2; ++c) {
        const u16* Asrc = Hb + (size_t)c * 8192 * HHH;
        u16* Cdst = P1 + (size_t)c * 8192 * HHH;
        k_gemm256<4><<<dim3(256), 512, 0, stream>>>(Asrc, W1T + oHP, lb + 1536, FFMc, PFF, HHH, 1, 8);
        k_gemm256<2><<<dim3(128), 512, 0, stream>>>(FFMc, W2T + oHP, lb + 4096, Cdst, HHH, PFF, 0, 4);
      }
    }
    // last ln_add writes the output directly (dtype-converted); others write Hb
    void* dd = (l == LLL - 1) ? d_out : nullptr;
    k_ln_add<<<NN, 256, 0, stream>>>(Hb, P1, ln2g, l * HHH, ln2b, l * HHH, Hb, dd, flagp);
  }
}

// Round 8
// 760.253 us; speedup vs baseline: 1.4480x; 1.4480x over previous
//
#include <hip/hip_runtime.h>

#define BB 32
#define SS 512
#define DD 256
#define HHH 512
#define NHH 8
#define HDD 64
#define PFF 2048
#define LLL 2
#define NN (BB*SS)      /* 16384 tokens */
#define NMAXX 15

typedef unsigned short u16;
typedef unsigned int u32;

typedef __attribute__((ext_vector_type(8))) __bf16 bf16x8;
typedef __attribute__((ext_vector_type(4))) float f32x4;

__device__ __forceinline__ float bf2f(u16 u) {
  union { u32 i; float f; } x; x.i = ((u32)u) << 16; return x.f;
}
__device__ __forceinline__ u16 f2bf(float f) {
  union { float f; u32 i; } x; x.f = f;
  u32 r = x.i + 0x7FFFu + ((x.i >> 16) & 1u);
  return (u16)(r >> 16);
}
// flag==1: inputs/outputs are bf16; flag==0: they are float32
__device__ __forceinline__ float ldf(const void* p, size_t i, int flag) {
  return flag ? bf2f(((const u16*)p)[i]) : ((const float*)p)[i];
}
__device__ __forceinline__ void stf(void* p, size_t i, int flag, float v) {
  if (flag) ((u16*)p)[i] = f2bf(v); else ((float*)p)[i] = v;
}
// async global->LDS, 16B per lane; LDS dest must be wave-uniform base + lane*16
__device__ __forceinline__ void gld16(const u16* g, u16* l) {
  __builtin_amdgcn_global_load_lds(
      (const __attribute__((address_space(1))) u32*)g,
      (__attribute__((address_space(3))) u32*)l, 16, 0, 0);
}

// ---------------- dtype probe: ln1_g[0] == 1.0 ----------------
__global__ void k_flag(const u32* __restrict__ ones, int* __restrict__ flag) {
  *flag = (ones[0] == 0x3F800000u) ? 0 : 1;
}

// ---------------- ALL weight transposes in ONE dispatch (6336 tiles, job ladder) ----------------
__global__ __launch_bounds__(256) void k_transpose_all(
    const void* __restrict__ socW, const void* __restrict__ projW,
    const void* __restrict__ Wq, const void* __restrict__ Wk,
    const void* __restrict__ Wv, const void* __restrict__ Wo,
    const void* __restrict__ W1, const void* __restrict__ W2,
    u16* __restrict__ socWT, u16* __restrict__ projWT, u16* __restrict__ WqkvT,
    u16* __restrict__ WoT, u16* __restrict__ W1T, u16* __restrict__ W2T,
    const int* __restrict__ flagp) {
  const size_t HH2 = (size_t)HHH * HHH, HP = (size_t)HHH * PFF;
  int bid = blockIdx.x;
  const void* in; size_t ioff; u16* out; int R, C;
  if (bid < 64)       { in = socW;  ioff = 0; out = socWT;  R = DD; C = DD;  }
  else if (bid < 192) { bid -= 64; in = projW; ioff = 0; out = projWT; R = DD; C = HHH; }
  else {
    int r = bid - 192;
    int l = r / 3072; r -= l * 3072;
    size_t oHH = (size_t)l * HH2, oHP = (size_t)l * HP;
    if (r < 256)       { in = Wq; ioff = oHH; out = WqkvT + (size_t)l*3*HH2;          R = HHH; C = HHH; bid = r; }
    else if (r < 512)  { in = Wk; ioff = oHH; out = WqkvT + (size_t)l*3*HH2 + HH2;    R = HHH; C = HHH; bid = r - 256; }
    else if (r < 768)  { in = Wv; ioff = oHH; out = WqkvT + (size_t)l*3*HH2 + 2*HH2;  R = HHH; C = HHH; bid = r - 512; }
    else if (r < 1024) { in = Wo; ioff = oHH; out = WoT + oHH;                        R = HHH; C = HHH; bid = r - 768; }
    else if (r < 2048) { in = W1; ioff = oHP; out = W1T + oHP;                        R = HHH; C = PFF; bid = r - 1024; }
    else               { in = W2; ioff = oHP; out = W2T + oHP;                        R = PFF; C = HHH; bid = r - 2048; }
  }
  int ntx = C >> 5;
  int c0 = (bid % ntx) * 32, r0 = (bid / ntx) * 32;
  __shared__ u16 tile[32][33];
  int flag = *flagp;
  int tx = threadIdx.x, ty = threadIdx.y;  // 32 x 8
  #pragma unroll
  for (int i = 0; i < 4; ++i)
    tile[ty + i*8][tx] = f2bf(ldf(in, ioff + (size_t)(r0 + ty + i*8) * C + c0 + tx, flag));
  __syncthreads();
  #pragma unroll
  for (int i = 0; i < 4; ++i) out[(size_t)(c0 + ty + i*8) * R + r0 + tx] = tile[tx][ty + i*8];
}

// ---------------- pack all biases to bf16 ----------------
// layout: [projb 512][per-layer: bq,bk,bv (1536) | b1 (2048) | bo (512) | b2 (512)]
__global__ __launch_bounds__(256) void k_packb(const void* __restrict__ projb,
    const void* __restrict__ bq, const void* __restrict__ bk, const void* __restrict__ bv,
    const void* __restrict__ b1, const void* __restrict__ bo, const void* __restrict__ b2,
    u16* __restrict__ out, const int* __restrict__ flagp) {
  int flag = *flagp;
  int i = blockIdx.x * 256 + threadIdx.x;
  int tot = 512 + LLL * 4608;
  if (i >= tot) return;
  float v;
  if (i < 512) v = ldf(projb, i, flag);
  else {
    int j = i - 512, l = j / 4608, r = j % 4608;
    if      (r < 512)  v = ldf(bq, (size_t)l * HHH + r, flag);
    else if (r < 1024) v = ldf(bk, (size_t)l * HHH + r - 512, flag);
    else if (r < 1536) v = ldf(bv, (size_t)l * HHH + r - 1024, flag);
    else if (r < 3584) v = ldf(b1, (size_t)l * PFF + r - 1536, flag);
    else if (r < 4096) v = ldf(bo, (size_t)l * HHH + r - 3584, flag);
    else               v = ldf(b2, (size_t)l * HHH + r - 4096, flag);
  }
  out[i] = f2bf(v);
}

// ---------------- PE + time-bias table: pet[s][d] = PE(s,d) + tB[d] ----------------
__global__ __launch_bounds__(256) void k_pe(const void* __restrict__ tB,
    u16* __restrict__ pet, const int* __restrict__ flagp) {
  int flag = *flagp;
  int s = blockIdx.x, d = threadIdx.x;
  int i2 = d & ~1;
  float freq = expf(-0.035977892078031968f * (float)i2);
  float ang = (float)s * freq;
  float v = ((d & 1) ? cosf(ang) : sinf(ang)) + ldf(tB, d, flag);
  pet[(size_t)s * DD + d] = f2bf(v);
}

// ---------------- embedding + PE table + time encoding (no trig) ----------------
__global__ __launch_bounds__(256) void k_embed(const int* __restrict__ src,
    const void* __restrict__ tiv, const void* __restrict__ emb,
    const void* __restrict__ tW, const u16* __restrict__ pet,
    u16* __restrict__ X, const int* __restrict__ flagp) {
  int flag = *flagp;
  int n = blockIdx.x, d = threadIdx.x;
  int s = n & (SS - 1);
  int tok = src[n];
  float v = ldf(emb, (size_t)tok * DD + d, flag);
  v += bf2f(pet[(size_t)s * DD + d]);
  float t = ldf(tiv, n, flag);
  v += t * ldf(tW, d, flag);
  X[(size_t)n * DD + d] = f2bf(v);
}

// ---------------- neighbor mean aggregation ----------------
__global__ __launch_bounds__(256) void k_agg(const int* __restrict__ nidx,
    const int* __restrict__ ncnt, const u16* __restrict__ X, u16* __restrict__ AGG) {
  int n = blockIdx.x, d = threadIdx.x;
  int cnt = ncnt[n];
  float s = 0.f;
  for (int j = 0; j < cnt; ++j) {
    int m = nidx[n * NMAXX + j];
    s += bf2f(X[(size_t)m * DD + d]);
  }
  float div = (float)(cnt > 0 ? cnt : 1);
  AGG[(size_t)n * DD + d] = f2bf(s / div);
}

// ---------------- m97-style bf16 MFMA GEMM (kept for soc, N=256) ----------------
__global__ __launch_bounds__(256) void k_gemm128(const u16* __restrict__ A,
    const u16* __restrict__ BT, const void* __restrict__ bias, int boff,
    const u16* __restrict__ res, u16* __restrict__ C, int N, int K, int relu,
    const int* __restrict__ flagp) {
  __shared__ __align__(16) u16 As[128 * 32];
  __shared__ __align__(16) u16 Bs[128 * 32];
  int n0 = blockIdx.x * 128, m0 = blockIdx.y * 128;
  int t = threadIdx.x;
  int lane = t & 63, w = t >> 6;
  int wm = (w >> 1) * 64, wn = (w & 1) * 64;
  int fr = lane & 15, fq = lane >> 4;
  int srow = t >> 2, sseg = t & 3;

  f32x4 acc[4][4];
  #pragma unroll
  for (int i = 0; i < 4; ++i)
    #pragma unroll
    for (int j = 0; j < 4; ++j) acc[i][j] = (f32x4){0.f, 0.f, 0.f, 0.f};

  const u16* ga = A  + (size_t)(m0 + srow) * K + sseg * 8;
  const u16* gb = BT + (size_t)(n0 + srow) * K + sseg * 8;
  u16* lA = As + srow * 32 + sseg * 8;
  u16* lB = Bs + srow * 32 + sseg * 8;
  const size_t rstride = (size_t)64 * K;

  for (int k0 = 0; k0 < K; k0 += 32) {
    gld16(ga + k0, lA);
    gld16(ga + k0 + rstride, lA + 64 * 32);
    gld16(gb + k0, lB);
    gld16(gb + k0 + rstride, lB + 64 * 32);
    __syncthreads();
    bf16x8 af[4], bf[4];
    #pragma unroll
    for (int i = 0; i < 4; ++i) af[i] = *(const bf16x8*)&As[(wm + i * 16 + fr) * 32 + fq * 8];
    #pragma unroll
    for (int j = 0; j < 4; ++j) bf[j] = *(const bf16x8*)&Bs[(wn + j * 16 + fr) * 32 + fq * 8];
    #pragma unroll
    for (int i = 0; i < 4; ++i)
      #pragma unroll
      for (int j = 0; j < 4; ++j)
        acc[i][j] = __builtin_amdgcn_mfma_f32_16x16x32_bf16(af[i], bf[j], acc[i][j], 0, 0, 0);
    __syncthreads();
  }

  int flag = *flagp;
  #pragma unroll
  for (int j = 0; j < 4; ++j) {
    int col = n0 + wn + j * 16 + fr;
    float bv = bias ? ldf(bias, boff + col, flag) : 0.f;
    #pragma unroll
    for (int i = 0; i < 4; ++i) {
      #pragma unroll
      for (int c = 0; c < 4; ++c) {
        int row = m0 + wm + i * 16 + fq * 4 + c;
        float v = acc[i][j][c] + bv;
        if (res) v += bf2f(res[(size_t)row * N + col]);
        if (relu) v = fmaxf(v, 0.f);
        C[(size_t)row * N + col] = f2bf(v);
      }
    }
  }
}

// ---------------- pipelined 256-row-tile GEMM: BM=256, BN=64*NBF, BK=32 ----------------
template<int NBF>
__global__ __launch_bounds__(512, 2) void k_gemm256(const u16* __restrict__ A,
    const u16* __restrict__ BT, const u16* __restrict__ bias,
    u16* __restrict__ C, int N, int K, int relu, int nbx) {
  constexpr int AG = 1024;
  constexpr int BG = NBF * 256;
  constexpr int STRIDE = (AG + BG) * 8;
  constexpr int LPT = 2 + BG / 512;
  __shared__ __align__(16) u16 S[3 * STRIDE];

  int nwg = gridDim.x;
  int id = blockIdx.x;
  int wg = ((nwg & 7) == 0) ? ((id & 7) * (nwg >> 3) + (id >> 3)) : id;
  int bx = wg % nbx, by = wg / nbx;
  int m0 = by * 256, n0 = bx * (64 * NBF);

  int t = threadIdx.x;
  int w = t >> 6, lane = t & 63;
  int fr = lane & 15, fq = lane >> 4;
  int wm = (w >> 2) * 128, wn = (w & 3) * (16 * NBF);
  int gsw8 = (fq ^ (fr & 3) ^ ((fr >> 2) & 3)) * 8;

  int arow = t >> 2, aseg = t & 3;
  int asw = aseg ^ (arow & 3) ^ ((arow >> 2) & 3);
  const u16* gA  = A  + (size_t)(m0 + arow) * K + asw * 8;
  const u16* gA2 = gA + (size_t)128 * K;
  const u16* gB  = BT + (size_t)(n0 + arow) * K + asw * 8;
  const u16* gB2 = gB + (size_t)128 * K;

  f32x4 acc[8][NBF];
  #pragma unroll
  for (int i = 0; i < 8; ++i)
    #pragma unroll
    for (int j = 0; j < NBF; ++j) acc[i][j] = (f32x4){0.f, 0.f, 0.f, 0.f};

  int NT = K >> 5;

  #pragma unroll
  for (int p = 0; p < 2; ++p) {
    gld16(gA  + p * 32, S + p * STRIDE + t * 8);
    gld16(gA2 + p * 32, S + p * STRIDE + (t + 512) * 8);
    gld16(gB  + p * 32, S + p * STRIDE + AG * 8 + t * 8);
    if constexpr (NBF == 4)
      gld16(gB2 + p * 32, S + p * STRIDE + AG * 8 + (t + 512) * 8);
  }
  asm volatile("s_waitcnt vmcnt(%0)" :: "n"(LPT) : "memory");
  __builtin_amdgcn_s_barrier();
  __builtin_amdgcn_sched_barrier(0);

  for (int T = 0; T < NT; ++T) {
    const u16* Sa = S + (T % 3) * STRIDE;
    const u16* Sb = Sa + AG * 8;
    u16* Sn = S + ((T + 2) % 3) * STRIDE;
    int kn = (T + 2) * 32;
    bool st = (T + 2) < NT;

    bf16x8 af[4], bf[NBF];
    #pragma unroll
    for (int i = 0; i < 4; ++i) af[i] = *(const bf16x8*)&Sa[(wm + i * 16 + fr) * 32 + gsw8];
    #pragma unroll
    for (int j = 0; j < NBF; ++j) bf[j] = *(const bf16x8*)&Sb[(wn + j * 16 + fr) * 32 + gsw8];
    if (st) {
      gld16(gA  + kn, Sn + t * 8);
      gld16(gA2 + kn, Sn + (t + 512) * 8);
    }
    __builtin_amdgcn_s_setprio(1);
    #pragma unroll
    for (int i = 0; i < 4; ++i)
      #pragma unroll
      for (int j = 0; j < NBF; ++j)
        acc[i][j] = __builtin_amdgcn_mfma_f32_16x16x32_bf16(af[i], bf[j], acc[i][j], 0, 0, 0);
    __builtin_amdgcn_s_setprio(0);

    bf16x8 ag[4];
    #pragma unroll
    for (int i = 0; i < 4; ++i) ag[i] = *(const bf16x8*)&Sa[(wm + 64 + i * 16 + fr) * 32 + gsw8];
    if (st) {
      gld16(gB + kn, Sn + AG * 8 + t * 8);
      if constexpr (NBF == 4)
        gld16(gB2 + kn, Sn + AG * 8 + (t + 512) * 8);
    }
    __builtin_amdgcn_s_setprio(1);
    #pragma unroll
    for (int i = 0; i < 4; ++i)
      #pragma unroll
      for (int j = 0; j < NBF; ++j)
        acc[4 + i][j] = __builtin_amdgcn_mfma_f32_16x16x32_bf16(ag[i], bf[j], acc[4 + i][j], 0, 0, 0);
    __builtin_amdgcn_s_setprio(0);

    if (st) { asm volatile("s_waitcnt vmcnt(%0) lgkmcnt(0)" :: "n"(LPT) : "memory"); }
    else    { asm volatile("s_waitcnt vmcnt(0) lgkmcnt(0)" ::: "memory"); }
    __builtin_amdgcn_s_barrier();
    __builtin_amdgcn_sched_barrier(0);
  }

  // epilogue: row-major store order for write combining
  float bvj[NBF];
  #pragma unroll
  for (int j = 0; j < NBF; ++j) bvj[j] = bf2f(bias[n0 + wn + j * 16 + fr]);
  #pragma unroll
  for (int i = 0; i < 8; ++i) {
    #pragma unroll
    for (int c = 0; c < 4; ++c) {
      size_t rowb = (size_t)(m0 + wm + i * 16 + fq * 4 + c) * N;
      #pragma unroll
      for (int j = 0; j < NBF; ++j) {
        int col = n0 + wn + j * 16 + fr;
        float v = acc[i][j][c] + bvj[j];
        if (relu) v = fmaxf(v, 0.f);
        C[rowb + col] = f2bf(v);
      }
    }
  }
}

// ---------------- soc LayerNorm(D=256) + relu + select + x += 0.2*soc ----------------
__global__ __launch_bounds__(256) void k_ln_soc(const u16* __restrict__ socp,
    const u16* __restrict__ X, const void* __restrict__ g, const void* __restrict__ beta,
    const int* __restrict__ ncnt, const int* __restrict__ src,
    u16* __restrict__ X2, void* __restrict__ dout, const int* __restrict__ flagp) {
  __shared__ float sred[4];
  int flag = *flagp;
  int n = blockIdx.x, t = threadIdx.x;
  size_t base = (size_t)n * DD;
  float v = bf2f(socp[base + t]);
  float s = v;
  #pragma unroll
  for (int o = 32; o; o >>= 1) s += __shfl_xor(s, o, 64);
  if ((t & 63) == 0) sred[t >> 6] = s;
  __syncthreads();
  float mean = (sred[0] + sred[1] + sred[2] + sred[3]) * (1.f / DD);
  float dv = v - mean;
  float q = dv * dv;
  #pragma unroll
  for (int o = 32; o; o >>= 1) q += __shfl_xor(q, o, 64);
  __syncthreads();
  if ((t & 63) == 0) sred[t >> 6] = q;
  __syncthreads();
  float var = (sred[0] + sred[1] + sred[2] + sred[3]) * (1.f / DD);
  float rs = rsqrtf(var + 1e-5f);
  float soc = fmaxf(dv * rs * ldf(g, t, flag) + ldf(beta, t, flag), 0.f);
  float xv = bf2f(X[base + t]);
  if (ncnt[n] <= 0) soc = xv;
  if (src[n] == 0)  soc = 0.f;
  float ov = xv + 0.2f * soc;
  X2[base + t] = f2bf(ov);
  stf(dout, (size_t)NN * HHH + base + t, flag, ov);
}

// ---------------- LayerNorm(H=512) of (a+b); out bf16, or dout (output dtype) ----------------
__global__ __launch_bounds__(256) void k_ln_add(const u16* __restrict__ a,
    const u16* __restrict__ b, const void* __restrict__ g, int goff,
    const void* __restrict__ bb, int boff, u16* __restrict__ out,
    void* __restrict__ dout, const int* __restrict__ flagp) {
  __shared__ float sred[4];
  int flag = *flagp;
  int row = blockIdx.x, t = threadIdx.x;
  size_t base = (size_t)row * HHH;
  float v0 = bf2f(a[base + t])       + bf2f(b[base + t]);
  float v1 = bf2f(a[base + 256 + t]) + bf2f(b[base + 256 + t]);
  float s = v0 + v1;
  #pragma unroll
  for (int o = 32; o; o >>= 1) s += __shfl_xor(s, o, 64);
  if ((t & 63) == 0) sred[t >> 6] = s;
  __syncthreads();
  float mean = (sred[0] + sred[1] + sred[2] + sred[3]) * (1.f / HHH);
  float d0 = v0 - mean, d1 = v1 - mean;
  float q = d0 * d0 + d1 * d1;
  #pragma unroll
  for (int o = 32; o; o >>= 1) q += __shfl_xor(q, o, 64);
  __syncthreads();
  if ((t & 63) == 0) sred[t >> 6] = q;
  __syncthreads();
  float var = (sred[0] + sred[1] + sred[2] + sred[3]) * (1.f / HHH);
  float rs = rsqrtf(var + 1e-5f);
  float o0 = d0 * rs * ldf(g, goff + t, flag)       + ldf(bb, boff + t, flag);
  float o1 = d1 * rs * ldf(g, goff + 256 + t, flag) + ldf(bb, boff + 256 + t, flag);
  if (dout) {
    stf(dout, base + t, flag, o0);
    stf(dout, base + 256 + t, flag, o1);
  } else {
    out[base + t]       = f2bf(o0);
    out[base + 256 + t] = f2bf(o1);
  }
}

// ---------------- MFMA attention: one block per (head, batch); Q/K/V strided (ld) ----------------
// R6-measured 62us version (verbatim). The R7 swapped-softmax variant spilled sacc to
// scratch (FETCH 37->369MB) -- do not restructure softmax without checking scratch usage.
__global__ __launch_bounds__(512, 2) void k_attn_mfma(const u16* __restrict__ Q,
    const u16* __restrict__ Kb, const u16* __restrict__ Vb, int ld,
    const int* __restrict__ src, u16* __restrict__ O) {
  __shared__ __align__(16) u16 Ks[512 * 64];
  __shared__ __align__(16) u16 VTs[64 * 512];
  __shared__ __align__(16) u16 Ps[128 * 72];
  __shared__ float maskv[512];
  int h = blockIdx.x, b = blockIdx.y;
  int t = threadIdx.x;
  int w = t >> 6, lane = t & 63;
  int fr = lane & 15, fq = lane >> 4;

  maskv[t] = (src[b * SS + t] != 0) ? 1.f : 0.f;

  #pragma unroll
  for (int i = 0; i < 8; ++i) {
    int off = t + i * 512;
    int row = off >> 3;
    int gs  = (off & 7) ^ (row & 7);
    gld16(Kb + (size_t)(b * SS + row) * ld + h * HDD + gs * 8, Ks + (size_t)off * 8);
  }
  {
    const u16* vsrc = Vb + (size_t)(b * SS + t) * ld + h * HDD;
    int ghi = (t >> 3) & ~7, glo = (t >> 3) & 7, kw = t & 7;
    #pragma unroll
    for (int i = 0; i < 8; ++i) {
      uint4 raw = *(const uint4*)(vsrc + i * 8);
      u16 e[8]; *(uint4*)e = raw;
      #pragma unroll
      for (int jj = 0; jj < 8; ++jj) {
        int d = i * 8 + jj;
        VTs[(size_t)d * 512 + (size_t)((ghi | (glo ^ (d & 7))) * 8 + kw)] = e[jj];
      }
    }
  }
  __syncthreads();

  for (int chunk = 0; chunk < 4; ++chunk) {
    int qb = chunk * 128 + w * 16;
    bf16x8 qf[2];
    #pragma unroll
    for (int kc = 0; kc < 2; ++kc)
      qf[kc] = *(const bf16x8*)&Q[(size_t)(b * SS + qb + fr) * ld + h * HDD + kc * 32 + fq * 8];

    f32x4 sacc[32];
    #pragma unroll
    for (int j = 0; j < 32; ++j) sacc[j] = (f32x4){0.f, 0.f, 0.f, 0.f};

    #pragma unroll
    for (int kt = 0; kt < 32; ++kt) {
      int row = kt * 16 + fr;
      #pragma unroll
      for (int kc = 0; kc < 2; ++kc) {
        bf16x8 kf = *(const bf16x8*)&Ks[(size_t)row * 64 +
            (size_t)(((kc * 4 + fq) ^ (fr & 7)) * 8)];
        sacc[kt] = __builtin_amdgcn_mfma_f32_16x16x32_bf16(qf[kc], kf, sacc[kt], 0, 0, 0);
      }
    }

    #pragma unroll
    for (int j = 0; j < 32; ++j) {
      float mv = maskv[j * 16 + fr];
      #pragma unroll
      for (int c = 0; c < 4; ++c) {
        float v = sacc[j][c] * 0.125f;
        sacc[j][c] = (mv != 0.f) ? v : -1e10f;
      }
    }
    #pragma unroll
    for (int c = 0; c < 4; ++c) {
      float m = -3.0e38f;
      #pragma unroll
      for (int j = 0; j < 32; ++j) m = fmaxf(m, sacc[j][c]);
      #pragma unroll
      for (int o = 1; o < 16; o <<= 1) m = fmaxf(m, __shfl_xor(m, o, 64));
      float s = 0.f;
      #pragma unroll
      for (int j = 0; j < 32; ++j) { float e = __expf(sacc[j][c] - m); sacc[j][c] = e; s += e; }
      #pragma unroll
      for (int o = 1; o < 16; o <<= 1) s += __shfl_xor(s, o, 64);
      float inv = 1.f / s;
      #pragma unroll
      for (int j = 0; j < 32; ++j) sacc[j][c] *= inv;
    }

    f32x4 oacc[4];
    #pragma unroll
    for (int n = 0; n < 4; ++n) oacc[n] = (f32x4){0.f, 0.f, 0.f, 0.f};

    #pragma unroll
    for (int seg = 0; seg < 8; ++seg) {
      #pragma unroll
      for (int tt = 0; tt < 4; ++tt)
        #pragma unroll
        for (int c = 0; c < 4; ++c)
          Ps[(size_t)(w * 16 + fq * 4 + c) * 72 + tt * 16 + fr] = f2bf(sacc[seg * 4 + tt][c]);
      #pragma unroll
      for (int kc = 0; kc < 2; ++kc) {
        bf16x8 pa = *(const bf16x8*)&Ps[(size_t)(w * 16 + fr) * 72 + kc * 32 + fq * 8];
        #pragma unroll
        for (int nt = 0; nt < 4; ++nt) {
          bf16x8 bv = *(const bf16x8*)&VTs[(size_t)(nt * 16 + fr) * 512 +
              (size_t)((seg * 8 + ((kc * 4 + fq) ^ (fr & 7))) * 8)];
          oacc[nt] = __builtin_amdgcn_mfma_f32_16x16x32_bf16(pa, bv, oacc[nt], 0, 0, 0);
        }
      }
    }

    #pragma unroll
    for (int nt = 0; nt < 4; ++nt)
      #pragma unroll
      for (int c = 0; c < 4; ++c)
        O[(size_t)(b * SS + qb + fq * 4 + c) * HHH + h * HDD + nt * 16 + fr] = f2bf(oacc[nt][c]);
  }
}

extern "C" void kernel_launch(void* const* d_in, const int* in_sizes, int n_in,
                              void* d_out, int out_size, void* d_ws, size_t ws_size,
                              hipStream_t stream) {
  (void)in_sizes; (void)n_in; (void)out_size;
  const int* src    = (const int*)d_in[0];
  const int* nidx   = (const int*)d_in[2];
  const int* ncnt   = (const int*)d_in[3];
  const void* tiv   = d_in[4];
  const void* emb   = d_in[5];
  const void* tW    = d_in[6];
  const void* tB    = d_in[7];
  const void* socW  = d_in[8];
  const void* socb  = d_in[9];
  const void* socg  = d_in[10];
  const void* socbe = d_in[11];
  const void* projW = d_in[12];
  const void* projb = d_in[13];
  const void* Wq    = d_in[14];
  const void* bq    = d_in[15];
  const void* Wk    = d_in[16];
  const void* bk    = d_in[17];
  const void* Wv    = d_in[18];
  const void* bv    = d_in[19];
  const void* Wo    = d_in[20];
  const void* bo    = d_in[21];
  const void* ln1g  = d_in[22];
  const void* ln1b  = d_in[23];
  const void* W1    = d_in[24];
  const void* b1    = d_in[25];
  const void* W2    = d_in[26];
  const void* b2    = d_in[27];
  const void* ln2g  = d_in[28];
  const void* ln2b  = d_in[29];

  const size_t NHS = (size_t)NN * HHH;
  const size_t QKV3 = (size_t)3 * HHH * HHH;
  u16* ws = (u16*)d_ws;
  u16* socWT  = ws;
  u16* projWT = socWT + (size_t)DD * DD;
  u16* WqkvT  = projWT + (size_t)DD * HHH;
  u16* WoT    = WqkvT + (size_t)LLL * QKV3;
  u16* W1T    = WoT + (size_t)LLL * HHH * HHH;
  u16* W2T    = W1T + (size_t)LLL * HHH * PFF;
  u16* Hb     = W2T + (size_t)LLL * HHH * PFF;
  u16* P1     = Hb + NHS;
  u16* P2     = P1 + NHS;
  u16* P3     = P2 + NHS;
  int* flagp  = (int*)(P3 + NHS);
  u16* packb  = (u16*)(flagp + 4);
  u16* pet    = packb + 16384;                    // PE table [512,256]
  u16* FFMf   = pet + (size_t)SS * DD;            // full FFM [16384,2048] (if ws allows)
  size_t need_full = (size_t)(FFMf - ws + (size_t)NN * PFF) * 2;
  int fullff = (ws_size >= need_full);

  u16* X    = P1;
  u16* AGG  = P2;
  u16* SOCP = P3;
  u16* X2   = P2;
  u16* Ob   = (u16*)d_out;
  u16* FFMc = P2;    // chunked fallback: [8192,2048] spans P2+P3

  k_flag<<<1, 1, 0, stream>>>((const u32*)ln1g, flagp);

  dim3 tb(32, 8);
  k_transpose_all<<<dim3(192 + LLL * 3072), tb, 0, stream>>>(
      socW, projW, Wq, Wk, Wv, Wo, W1, W2,
      socWT, projWT, WqkvT, WoT, W1T, W2T, flagp);
  k_packb<<<dim3((512 + LLL * 4608 + 255) / 256), 256, 0, stream>>>(
      projb, bq, bk, bv, b1, bo, b2, packb, flagp);
  k_pe<<<SS, 256, 0, stream>>>(tB, pet, flagp);

  k_embed<<<NN, 256, 0, stream>>>(src, tiv, emb, tW, pet, X, flagp);
  k_agg<<<NN, 256, 0, stream>>>(nidx, ncnt, X, AGG);
  k_gemm128<<<dim3(DD / 128, NN / 128), 256, 0, stream>>>(AGG, socWT, socb, 0, X, SOCP, DD, DD, 0, flagp);
  k_ln_soc<<<NN, 256, 0, stream>>>(SOCP, X, socg, socbe, ncnt, src, X2, d_out, flagp);
  // proj: [16384,256] @ [256,512] -> Hb
  k_gemm256<2><<<dim3(256), 512, 0, stream>>>(X2, projWT, packb, Hb, HHH, DD, 0, 4);

  for (int l = 0; l < LLL; ++l) {
    size_t oHH = (size_t)l * HHH * HHH, oHP = (size_t)l * HHH * PFF;
    u16* lb = packb + 512 + (size_t)l * 4608;
    // fused QKV: [16384,512] @ [512,1536] -> P1 (row stride 1536, spans P1..P3)
    k_gemm256<4><<<dim3(384), 512, 0, stream>>>(Hb, WqkvT + (size_t)l * QKV3, lb, P1, 1536, HHH, 0, 6);
    k_attn_mfma<<<dim3(NHH, BB), 512, 0, stream>>>(P1, P1 + HHH, P1 + 2 * HHH, 3 * HHH, src, Ob);
    // Wo: [16384,512] @ [512,512] -> P1
    k_gemm256<2><<<dim3(256), 512, 0, stream>>>(Ob, WoT + oHH, lb + 3584, P1, HHH, HHH, 0, 4);
    k_ln_add<<<NN, 256, 0, stream>>>(Hb, P1, ln1g, l * HHH, ln1b, l * HHH, Hb, nullptr, flagp);
    if (fullff) {
      // FF1: [16384,512]@[512,2048] -> FFMf (grid 512); FF2: -> P1 (grid 256, FULL occupancy)
      k_gemm256<4><<<dim3(512), 512, 0, stream>>>(Hb, W1T + oHP, lb + 1536, FFMf, PFF, HHH, 1, 8);
      k_gemm256<2><<<dim3(256), 512, 0, stream>>>(FFMf, W2T + oHP, lb + 4096, P1, HHH, PFF, 0, 4);
    } else {
      for (int c = 0; c < 2; ++c) {
        const u16* Asrc = Hb + (size_t)c * 8192 * HHH;
        u16* Cdst = P1 + (size_t)c * 8192 * HHH;
        k_gemm256<4><<<dim3(256), 512, 0, stream>>>(Asrc, W1T + oHP, lb + 1536, FFMc, PFF, HHH, 1, 8);
        k_gemm256<2><<<dim3(128), 512, 0, stream>>>(FFMc, W2T + oHP, lb + 4096, Cdst, HHH, PFF, 0, 4);
      }
    }
    // last ln_add writes the output directly (dtype-converted); others write Hb
    void* dd = (l == LLL - 1) ? d_out : nullptr;
    k_ln_add<<<NN, 256, 0, stream>>>(Hb, P1, ln2g, l * HHH, ln2b, l * HHH, Hb, dd, flagp);
  }
}

// Round 9
// 740.814 us; speedup vs baseline: 1.4860x; 1.0262x over previous
//
#include <hip/hip_runtime.h>

#define BB 32
#define SS 512
#define DD 256
#define HHH 512
#define NHH 8
#define HDD 64
#define PFF 2048
#define LLL 2
#define NN (BB*SS)      /* 16384 tokens */
#define NMAXX 15

typedef unsigned short u16;
typedef unsigned int u32;

typedef __attribute__((ext_vector_type(8))) __bf16 bf16x8;
typedef __attribute__((ext_vector_type(4))) float f32x4;

__device__ __forceinline__ float bf2f(u16 u) {
  union { u32 i; float f; } x; x.i = ((u32)u) << 16; return x.f;
}
__device__ __forceinline__ u16 f2bf(float f) {
  union { float f; u32 i; } x; x.f = f;
  u32 r = x.i + 0x7FFFu + ((x.i >> 16) & 1u);
  return (u16)(r >> 16);
}
// flag==1: inputs/outputs are bf16; flag==0: they are float32
__device__ __forceinline__ float ldf(const void* p, size_t i, int flag) {
  return flag ? bf2f(((const u16*)p)[i]) : ((const float*)p)[i];
}
__device__ __forceinline__ void stf(void* p, size_t i, int flag, float v) {
  if (flag) ((u16*)p)[i] = f2bf(v); else ((float*)p)[i] = v;
}
// async global->LDS, 16B per lane; LDS dest must be wave-uniform base + lane*16
__device__ __forceinline__ void gld16(const u16* g, u16* l) {
  __builtin_amdgcn_global_load_lds(
      (const __attribute__((address_space(1))) u32*)g,
      (__attribute__((address_space(3))) u32*)l, 16, 0, 0);
}

// ---------------- dtype probe: ln1_g[0] == 1.0 ----------------
__global__ void k_flag(const u32* __restrict__ ones, int* __restrict__ flag) {
  *flag = (ones[0] == 0x3F800000u) ? 0 : 1;
}

// ---------------- ALL weight transposes in ONE dispatch (6336 tiles, job ladder) ----------------
__global__ __launch_bounds__(256) void k_transpose_all(
    const void* __restrict__ socW, const void* __restrict__ projW,
    const void* __restrict__ Wq, const void* __restrict__ Wk,
    const void* __restrict__ Wv, const void* __restrict__ Wo,
    const void* __restrict__ W1, const void* __restrict__ W2,
    u16* __restrict__ socWT, u16* __restrict__ projWT, u16* __restrict__ WqkvT,
    u16* __restrict__ WoT, u16* __restrict__ W1T, u16* __restrict__ W2T,
    const int* __restrict__ flagp) {
  const size_t HH2 = (size_t)HHH * HHH, HP = (size_t)HHH * PFF;
  int bid = blockIdx.x;
  const void* in; size_t ioff; u16* out; int R, C;
  if (bid < 64)       { in = socW;  ioff = 0; out = socWT;  R = DD; C = DD;  }
  else if (bid < 192) { bid -= 64; in = projW; ioff = 0; out = projWT; R = DD; C = HHH; }
  else {
    int r = bid - 192;
    int l = r / 3072; r -= l * 3072;
    size_t oHH = (size_t)l * HH2, oHP = (size_t)l * HP;
    if (r < 256)       { in = Wq; ioff = oHH; out = WqkvT + (size_t)l*3*HH2;          R = HHH; C = HHH; bid = r; }
    else if (r < 512)  { in = Wk; ioff = oHH; out = WqkvT + (size_t)l*3*HH2 + HH2;    R = HHH; C = HHH; bid = r - 256; }
    else if (r < 768)  { in = Wv; ioff = oHH; out = WqkvT + (size_t)l*3*HH2 + 2*HH2;  R = HHH; C = HHH; bid = r - 512; }
    else if (r < 1024) { in = Wo; ioff = oHH; out = WoT + oHH;                        R = HHH; C = HHH; bid = r - 768; }
    else if (r < 2048) { in = W1; ioff = oHP; out = W1T + oHP;                        R = HHH; C = PFF; bid = r - 1024; }
    else               { in = W2; ioff = oHP; out = W2T + oHP;                        R = PFF; C = HHH; bid = r - 2048; }
  }
  int ntx = C >> 5;
  int c0 = (bid % ntx) * 32, r0 = (bid / ntx) * 32;
  __shared__ u16 tile[32][33];
  int flag = *flagp;
  int tx = threadIdx.x, ty = threadIdx.y;  // 32 x 8
  #pragma unroll
  for (int i = 0; i < 4; ++i)
    tile[ty + i*8][tx] = f2bf(ldf(in, ioff + (size_t)(r0 + ty + i*8) * C + c0 + tx, flag));
  __syncthreads();
  #pragma unroll
  for (int i = 0; i < 4; ++i) out[(size_t)(c0 + ty + i*8) * R + r0 + tx] = tile[tx][ty + i*8];
}

// ---------------- pack all biases to bf16 ----------------
// layout: [projb 512][per-layer: bq,bk,bv (1536) | b1 (2048) | bo (512) | b2 (512)]
__global__ __launch_bounds__(256) void k_packb(const void* __restrict__ projb,
    const void* __restrict__ bq, const void* __restrict__ bk, const void* __restrict__ bv,
    const void* __restrict__ b1, const void* __restrict__ bo, const void* __restrict__ b2,
    u16* __restrict__ out, const int* __restrict__ flagp) {
  int flag = *flagp;
  int i = blockIdx.x * 256 + threadIdx.x;
  int tot = 512 + LLL * 4608;
  if (i >= tot) return;
  float v;
  if (i < 512) v = ldf(projb, i, flag);
  else {
    int j = i - 512, l = j / 4608, r = j % 4608;
    if      (r < 512)  v = ldf(bq, (size_t)l * HHH + r, flag);
    else if (r < 1024) v = ldf(bk, (size_t)l * HHH + r - 512, flag);
    else if (r < 1536) v = ldf(bv, (size_t)l * HHH + r - 1024, flag);
    else if (r < 3584) v = ldf(b1, (size_t)l * PFF + r - 1536, flag);
    else if (r < 4096) v = ldf(bo, (size_t)l * HHH + r - 3584, flag);
    else               v = ldf(b2, (size_t)l * HHH + r - 4096, flag);
  }
  out[i] = f2bf(v);
}

// ---------------- PE + time-bias table: pet[s][d] = PE(s,d) + tB[d] ----------------
__global__ __launch_bounds__(256) void k_pe(const void* __restrict__ tB,
    u16* __restrict__ pet, const int* __restrict__ flagp) {
  int flag = *flagp;
  int s = blockIdx.x, d = threadIdx.x;
  int i2 = d & ~1;
  float freq = expf(-0.035977892078031968f * (float)i2);
  float ang = (float)s * freq;
  float v = ((d & 1) ? cosf(ang) : sinf(ang)) + ldf(tB, d, flag);
  pet[(size_t)s * DD + d] = f2bf(v);
}

// ---------------- embedding + PE table + time encoding (no trig) ----------------
__global__ __launch_bounds__(256) void k_embed(const int* __restrict__ src,
    const void* __restrict__ tiv, const void* __restrict__ emb,
    const void* __restrict__ tW, const u16* __restrict__ pet,
    u16* __restrict__ X, const int* __restrict__ flagp) {
  int flag = *flagp;
  int n = blockIdx.x, d = threadIdx.x;
  int s = n & (SS - 1);
  int tok = src[n];
  float v = ldf(emb, (size_t)tok * DD + d, flag);
  v += bf2f(pet[(size_t)s * DD + d]);
  float t = ldf(tiv, n, flag);
  v += t * ldf(tW, d, flag);
  X[(size_t)n * DD + d] = f2bf(v);
}

// ---------------- neighbor mean aggregation (vectorized: 32 lanes x 16B per row) ----------------
// 8 tokens per block; per token a 32-lane group reads whole 512B rows as uint4.
__global__ __launch_bounds__(256) void k_agg(const int* __restrict__ nidx,
    const int* __restrict__ ncnt, const u16* __restrict__ X, u16* __restrict__ AGG) {
  int g = threadIdx.x >> 5;          // token group 0..7
  int l32 = threadIdx.x & 31;        // lane covers channels l32*8 .. +7
  int n = blockIdx.x * 8 + g;
  int cnt = ncnt[n];
  float acc[8] = {0.f, 0.f, 0.f, 0.f, 0.f, 0.f, 0.f, 0.f};
  for (int j = 0; j < cnt; ++j) {
    int m = nidx[n * NMAXX + j];
    uint4 raw = *(const uint4*)&X[(size_t)m * DD + l32 * 8];
    u16 e[8]; *(uint4*)e = raw;
    #pragma unroll
    for (int k = 0; k < 8; ++k) acc[k] += bf2f(e[k]);
  }
  float inv = 1.f / (float)(cnt > 0 ? cnt : 1);
  u16 o[8];
  #pragma unroll
  for (int k = 0; k < 8; ++k) o[k] = f2bf(acc[k] * inv);
  *(uint4*)&AGG[(size_t)n * DD + l32 * 8] = *(uint4*)o;
}

// ---------------- m97-style bf16 MFMA GEMM (kept for soc, N=256) ----------------
__global__ __launch_bounds__(256) void k_gemm128(const u16* __restrict__ A,
    const u16* __restrict__ BT, const void* __restrict__ bias, int boff,
    const u16* __restrict__ res, u16* __restrict__ C, int N, int K, int relu,
    const int* __restrict__ flagp) {
  __shared__ __align__(16) u16 As[128 * 32];
  __shared__ __align__(16) u16 Bs[128 * 32];
  int n0 = blockIdx.x * 128, m0 = blockIdx.y * 128;
  int t = threadIdx.x;
  int lane = t & 63, w = t >> 6;
  int wm = (w >> 1) * 64, wn = (w & 1) * 64;
  int fr = lane & 15, fq = lane >> 4;
  int srow = t >> 2, sseg = t & 3;

  f32x4 acc[4][4];
  #pragma unroll
  for (int i = 0; i < 4; ++i)
    #pragma unroll
    for (int j = 0; j < 4; ++j) acc[i][j] = (f32x4){0.f, 0.f, 0.f, 0.f};

  const u16* ga = A  + (size_t)(m0 + srow) * K + sseg * 8;
  const u16* gb = BT + (size_t)(n0 + srow) * K + sseg * 8;
  u16* lA = As + srow * 32 + sseg * 8;
  u16* lB = Bs + srow * 32 + sseg * 8;
  const size_t rstride = (size_t)64 * K;

  for (int k0 = 0; k0 < K; k0 += 32) {
    gld16(ga + k0, lA);
    gld16(ga + k0 + rstride, lA + 64 * 32);
    gld16(gb + k0, lB);
    gld16(gb + k0 + rstride, lB + 64 * 32);
    __syncthreads();
    bf16x8 af[4], bf[4];
    #pragma unroll
    for (int i = 0; i < 4; ++i) af[i] = *(const bf16x8*)&As[(wm + i * 16 + fr) * 32 + fq * 8];
    #pragma unroll
    for (int j = 0; j < 4; ++j) bf[j] = *(const bf16x8*)&Bs[(wn + j * 16 + fr) * 32 + fq * 8];
    #pragma unroll
    for (int i = 0; i < 4; ++i)
      #pragma unroll
      for (int j = 0; j < 4; ++j)
        acc[i][j] = __builtin_amdgcn_mfma_f32_16x16x32_bf16(af[i], bf[j], acc[i][j], 0, 0, 0);
    __syncthreads();
  }

  int flag = *flagp;
  #pragma unroll
  for (int j = 0; j < 4; ++j) {
    int col = n0 + wn + j * 16 + fr;
    float bv = bias ? ldf(bias, boff + col, flag) : 0.f;
    #pragma unroll
    for (int i = 0; i < 4; ++i) {
      #pragma unroll
      for (int c = 0; c < 4; ++c) {
        int row = m0 + wm + i * 16 + fq * 4 + c;
        float v = acc[i][j][c] + bv;
        if (res) v += bf2f(res[(size_t)row * N + col]);
        if (relu) v = fmaxf(v, 0.f);
        C[(size_t)row * N + col] = f2bf(v);
      }
    }
  }
}

// ---------------- pipelined 256-row-tile GEMM: BM=256, BN=64*NBF, BK=32 ----------------
// NBF=2: LDS 72KB -> 2 blocks/CU (cross-block overlap hides barrier stalls).
// NBF=4: LDS 96KB -> 1 block/CU; use only when grid would otherwise be tiny.
template<int NBF>
__global__ __launch_bounds__(512, 2) void k_gemm256(const u16* __restrict__ A,
    const u16* __restrict__ BT, const u16* __restrict__ bias,
    u16* __restrict__ C, int N, int K, int relu, int nbx) {
  constexpr int AG = 1024;
  constexpr int BG = NBF * 256;
  constexpr int STRIDE = (AG + BG) * 8;
  constexpr int LPT = 2 + BG / 512;
  __shared__ __align__(16) u16 S[3 * STRIDE];

  int nwg = gridDim.x;
  int id = blockIdx.x;
  int wg = ((nwg & 7) == 0) ? ((id & 7) * (nwg >> 3) + (id >> 3)) : id;
  int bx = wg % nbx, by = wg / nbx;
  int m0 = by * 256, n0 = bx * (64 * NBF);

  int t = threadIdx.x;
  int w = t >> 6, lane = t & 63;
  int fr = lane & 15, fq = lane >> 4;
  int wm = (w >> 2) * 128, wn = (w & 3) * (16 * NBF);
  int gsw8 = (fq ^ (fr & 3) ^ ((fr >> 2) & 3)) * 8;

  int arow = t >> 2, aseg = t & 3;
  int asw = aseg ^ (arow & 3) ^ ((arow >> 2) & 3);
  const u16* gA  = A  + (size_t)(m0 + arow) * K + asw * 8;
  const u16* gA2 = gA + (size_t)128 * K;
  const u16* gB  = BT + (size_t)(n0 + arow) * K + asw * 8;
  const u16* gB2 = gB + (size_t)128 * K;

  f32x4 acc[8][NBF];
  #pragma unroll
  for (int i = 0; i < 8; ++i)
    #pragma unroll
    for (int j = 0; j < NBF; ++j) acc[i][j] = (f32x4){0.f, 0.f, 0.f, 0.f};

  int NT = K >> 5;

  #pragma unroll
  for (int p = 0; p < 2; ++p) {
    gld16(gA  + p * 32, S + p * STRIDE + t * 8);
    gld16(gA2 + p * 32, S + p * STRIDE + (t + 512) * 8);
    gld16(gB  + p * 32, S + p * STRIDE + AG * 8 + t * 8);
    if constexpr (NBF == 4)
      gld16(gB2 + p * 32, S + p * STRIDE + AG * 8 + (t + 512) * 8);
  }
  asm volatile("s_waitcnt vmcnt(%0)" :: "n"(LPT) : "memory");
  __builtin_amdgcn_s_barrier();
  __builtin_amdgcn_sched_barrier(0);

  for (int T = 0; T < NT; ++T) {
    const u16* Sa = S + (T % 3) * STRIDE;
    const u16* Sb = Sa + AG * 8;
    u16* Sn = S + ((T + 2) % 3) * STRIDE;
    int kn = (T + 2) * 32;
    bool st = (T + 2) < NT;

    bf16x8 af[4], bf[NBF];
    #pragma unroll
    for (int i = 0; i < 4; ++i) af[i] = *(const bf16x8*)&Sa[(wm + i * 16 + fr) * 32 + gsw8];
    #pragma unroll
    for (int j = 0; j < NBF; ++j) bf[j] = *(const bf16x8*)&Sb[(wn + j * 16 + fr) * 32 + gsw8];
    if (st) {
      gld16(gA  + kn, Sn + t * 8);
      gld16(gA2 + kn, Sn + (t + 512) * 8);
    }
    __builtin_amdgcn_s_setprio(1);
    #pragma unroll
    for (int i = 0; i < 4; ++i)
      #pragma unroll
      for (int j = 0; j < NBF; ++j)
        acc[i][j] = __builtin_amdgcn_mfma_f32_16x16x32_bf16(af[i], bf[j], acc[i][j], 0, 0, 0);
    __builtin_amdgcn_s_setprio(0);

    bf16x8 ag[4];
    #pragma unroll
    for (int i = 0; i < 4; ++i) ag[i] = *(const bf16x8*)&Sa[(wm + 64 + i * 16 + fr) * 32 + gsw8];
    if (st) {
      gld16(gB + kn, Sn + AG * 8 + t * 8);
      if constexpr (NBF == 4)
        gld16(gB2 + kn, Sn + AG * 8 + (t + 512) * 8);
    }
    __builtin_amdgcn_s_setprio(1);
    #pragma unroll
    for (int i = 0; i < 4; ++i)
      #pragma unroll
      for (int j = 0; j < NBF; ++j)
        acc[4 + i][j] = __builtin_amdgcn_mfma_f32_16x16x32_bf16(ag[i], bf[j], acc[4 + i][j], 0, 0, 0);
    __builtin_amdgcn_s_setprio(0);

    if (st) { asm volatile("s_waitcnt vmcnt(%0) lgkmcnt(0)" :: "n"(LPT) : "memory"); }
    else    { asm volatile("s_waitcnt vmcnt(0) lgkmcnt(0)" ::: "memory"); }
    __builtin_amdgcn_s_barrier();
    __builtin_amdgcn_sched_barrier(0);
  }

  // epilogue: row-major store order for write combining
  float bvj[NBF];
  #pragma unroll
  for (int j = 0; j < NBF; ++j) bvj[j] = bf2f(bias[n0 + wn + j * 16 + fr]);
  #pragma unroll
  for (int i = 0; i < 8; ++i) {
    #pragma unroll
    for (int c = 0; c < 4; ++c) {
      size_t rowb = (size_t)(m0 + wm + i * 16 + fq * 4 + c) * N;
      #pragma unroll
      for (int j = 0; j < NBF; ++j) {
        int col = n0 + wn + j * 16 + fr;
        float v = acc[i][j][c] + bvj[j];
        if (relu) v = fmaxf(v, 0.f);
        C[rowb + col] = f2bf(v);
      }
    }
  }
}

// ---------------- soc LayerNorm(D=256) + relu + select + x += 0.2*soc ----------------
__global__ __launch_bounds__(256) void k_ln_soc(const u16* __restrict__ socp,
    const u16* __restrict__ X, const void* __restrict__ g, const void* __restrict__ beta,
    const int* __restrict__ ncnt, const int* __restrict__ src,
    u16* __restrict__ X2, void* __restrict__ dout, const int* __restrict__ flagp) {
  __shared__ float sred[4];
  int flag = *flagp;
  int n = blockIdx.x, t = threadIdx.x;
  size_t base = (size_t)n * DD;
  float v = bf2f(socp[base + t]);
  float s = v;
  #pragma unroll
  for (int o = 32; o; o >>= 1) s += __shfl_xor(s, o, 64);
  if ((t & 63) == 0) sred[t >> 6] = s;
  __syncthreads();
  float mean = (sred[0] + sred[1] + sred[2] + sred[3]) * (1.f / DD);
  float dv = v - mean;
  float q = dv * dv;
  #pragma unroll
  for (int o = 32; o; o >>= 1) q += __shfl_xor(q, o, 64);
  __syncthreads();
  if ((t & 63) == 0) sred[t >> 6] = q;
  __syncthreads();
  float var = (sred[0] + sred[1] + sred[2] + sred[3]) * (1.f / DD);
  float rs = rsqrtf(var + 1e-5f);
  float soc = fmaxf(dv * rs * ldf(g, t, flag) + ldf(beta, t, flag), 0.f);
  float xv = bf2f(X[base + t]);
  if (ncnt[n] <= 0) soc = xv;
  if (src[n] == 0)  soc = 0.f;
  float ov = xv + 0.2f * soc;
  X2[base + t] = f2bf(ov);
  stf(dout, (size_t)NN * HHH + base + t, flag, ov);
}

// ---------------- LayerNorm(H=512) of (a+b); out bf16, or dout (output dtype) ----------------
__global__ __launch_bounds__(256) void k_ln_add(const u16* __restrict__ a,
    const u16* __restrict__ b, const void* __restrict__ g, int goff,
    const void* __restrict__ bb, int boff, u16* __restrict__ out,
    void* __restrict__ dout, const int* __restrict__ flagp) {
  __shared__ float sred[4];
  int flag = *flagp;
  int row = blockIdx.x, t = threadIdx.x;
  size_t base = (size_t)row * HHH;
  float v0 = bf2f(a[base + t])       + bf2f(b[base + t]);
  float v1 = bf2f(a[base + 256 + t]) + bf2f(b[base + 256 + t]);
  float s = v0 + v1;
  #pragma unroll
  for (int o = 32; o; o >>= 1) s += __shfl_xor(s, o, 64);
  if ((t & 63) == 0) sred[t >> 6] = s;
  __syncthreads();
  float mean = (sred[0] + sred[1] + sred[2] + sred[3]) * (1.f / HHH);
  float d0 = v0 - mean, d1 = v1 - mean;
  float q = d0 * d0 + d1 * d1;
  #pragma unroll
  for (int o = 32; o; o >>= 1) q += __shfl_xor(q, o, 64);
  __syncthreads();
  if ((t & 63) == 0) sred[t >> 6] = q;
  __syncthreads();
  float var = (sred[0] + sred[1] + sred[2] + sred[3]) * (1.f / HHH);
  float rs = rsqrtf(var + 1e-5f);
  float o0 = d0 * rs * ldf(g, goff + t, flag)       + ldf(bb, boff + t, flag);
  float o1 = d1 * rs * ldf(g, goff + 256 + t, flag) + ldf(bb, boff + 256 + t, flag);
  if (dout) {
    stf(dout, base + t, flag, o0);
    stf(dout, base + 256 + t, flag, o1);
  } else {
    out[base + t]       = f2bf(o0);
    out[base + 256 + t] = f2bf(o1);
  }
}

// ---------------- MFMA attention: one block per (head, batch); Q/K/V strided (ld) ----------------
// R6-measured 62us version (verbatim). The R7 swapped-softmax variant spilled sacc to
// scratch (FETCH 37->369MB) -- do not restructure softmax without checking scratch usage.
__global__ __launch_bounds__(512, 2) void k_attn_mfma(const u16* __restrict__ Q,
    const u16* __restrict__ Kb, const u16* __restrict__ Vb, int ld,
    const int* __restrict__ src, u16* __restrict__ O) {
  __shared__ __align__(16) u16 Ks[512 * 64];
  __shared__ __align__(16) u16 VTs[64 * 512];
  __shared__ __align__(16) u16 Ps[128 * 72];
  __shared__ float maskv[512];
  int h = blockIdx.x, b = blockIdx.y;
  int t = threadIdx.x;
  int w = t >> 6, lane = t & 63;
  int fr = lane & 15, fq = lane >> 4;

  maskv[t] = (src[b * SS + t] != 0) ? 1.f : 0.f;

  #pragma unroll
  for (int i = 0; i < 8; ++i) {
    int off = t + i * 512;
    int row = off >> 3;
    int gs  = (off & 7) ^ (row & 7);
    gld16(Kb + (size_t)(b * SS + row) * ld + h * HDD + gs * 8, Ks + (size_t)off * 8);
  }
  {
    const u16* vsrc = Vb + (size_t)(b * SS + t) * ld + h * HDD;
    int ghi = (t >> 3) & ~7, glo = (t >> 3) & 7, kw = t & 7;
    #pragma unroll
    for (int i = 0; i < 8; ++i) {
      uint4 raw = *(const uint4*)(vsrc + i * 8);
      u16 e[8]; *(uint4*)e = raw;
      #pragma unroll
      for (int jj = 0; jj < 8; ++jj) {
        int d = i * 8 + jj;
        VTs[(size_t)d * 512 + (size_t)((ghi | (glo ^ (d & 7))) * 8 + kw)] = e[jj];
      }
    }
  }
  __syncthreads();

  for (int chunk = 0; chunk < 4; ++chunk) {
    int qb = chunk * 128 + w * 16;
    bf16x8 qf[2];
    #pragma unroll
    for (int kc = 0; kc < 2; ++kc)
      qf[kc] = *(const bf16x8*)&Q[(size_t)(b * SS + qb + fr) * ld + h * HDD + kc * 32 + fq * 8];

    f32x4 sacc[32];
    #pragma unroll
    for (int j = 0; j < 32; ++j) sacc[j] = (f32x4){0.f, 0.f, 0.f, 0.f};

    #pragma unroll
    for (int kt = 0; kt < 32; ++kt) {
      int row = kt * 16 + fr;
      #pragma unroll
      for (int kc = 0; kc < 2; ++kc) {
        bf16x8 kf = *(const bf16x8*)&Ks[(size_t)row * 64 +
            (size_t)(((kc * 4 + fq) ^ (fr & 7)) * 8)];
        sacc[kt] = __builtin_amdgcn_mfma_f32_16x16x32_bf16(qf[kc], kf, sacc[kt], 0, 0, 0);
      }
    }

    #pragma unroll
    for (int j = 0; j < 32; ++j) {
      float mv = maskv[j * 16 + fr];
      #pragma unroll
      for (int c = 0; c < 4; ++c) {
        float v = sacc[j][c] * 0.125f;
        sacc[j][c] = (mv != 0.f) ? v : -1e10f;
      }
    }
    #pragma unroll
    for (int c = 0; c < 4; ++c) {
      float m = -3.0e38f;
      #pragma unroll
      for (int j = 0; j < 32; ++j) m = fmaxf(m, sacc[j][c]);
      #pragma unroll
      for (int o = 1; o < 16; o <<= 1) m = fmaxf(m, __shfl_xor(m, o, 64));
      float s = 0.f;
      #pragma unroll
      for (int j = 0; j < 32; ++j) { float e = __expf(sacc[j][c] - m); sacc[j][c] = e; s += e; }
      #pragma unroll
      for (int o = 1; o < 16; o <<= 1) s += __shfl_xor(s, o, 64);
      float inv = 1.f / s;
      #pragma unroll
      for (int j = 0; j < 32; ++j) sacc[j][c] *= inv;
    }

    f32x4 oacc[4];
    #pragma unroll
    for (int n = 0; n < 4; ++n) oacc[n] = (f32x4){0.f, 0.f, 0.f, 0.f};

    #pragma unroll
    for (int seg = 0; seg < 8; ++seg) {
      #pragma unroll
      for (int tt = 0; tt < 4; ++tt)
        #pragma unroll
        for (int c = 0; c < 4; ++c)
          Ps[(size_t)(w * 16 + fq * 4 + c) * 72 + tt * 16 + fr] = f2bf(sacc[seg * 4 + tt][c]);
      #pragma unroll
      for (int kc = 0; kc < 2; ++kc) {
        bf16x8 pa = *(const bf16x8*)&Ps[(size_t)(w * 16 + fr) * 72 + kc * 32 + fq * 8];
        #pragma unroll
        for (int nt = 0; nt < 4; ++nt) {
          bf16x8 bv = *(const bf16x8*)&VTs[(size_t)(nt * 16 + fr) * 512 +
              (size_t)((seg * 8 + ((kc * 4 + fq) ^ (fr & 7))) * 8)];
          oacc[nt] = __builtin_amdgcn_mfma_f32_16x16x32_bf16(pa, bv, oacc[nt], 0, 0, 0);
        }
      }
    }

    #pragma unroll
    for (int nt = 0; nt < 4; ++nt)
      #pragma unroll
      for (int c = 0; c < 4; ++c)
        O[(size_t)(b * SS + qb + fq * 4 + c) * HHH + h * HDD + nt * 16 + fr] = f2bf(oacc[nt][c]);
  }
}

extern "C" void kernel_launch(void* const* d_in, const int* in_sizes, int n_in,
                              void* d_out, int out_size, void* d_ws, size_t ws_size,
                              hipStream_t stream) {
  (void)in_sizes; (void)n_in; (void)out_size;
  const int* src    = (const int*)d_in[0];
  const int* nidx   = (const int*)d_in[2];
  const int* ncnt   = (const int*)d_in[3];
  const void* tiv   = d_in[4];
  const void* emb   = d_in[5];
  const void* tW    = d_in[6];
  const void* tB    = d_in[7];
  const void* socW  = d_in[8];
  const void* socb  = d_in[9];
  const void* socg  = d_in[10];
  const void* socbe = d_in[11];
  const void* projW = d_in[12];
  const void* projb = d_in[13];
  const void* Wq    = d_in[14];
  const void* bq    = d_in[15];
  const void* Wk    = d_in[16];
  const void* bk    = d_in[17];
  const void* Wv    = d_in[18];
  const void* bv    = d_in[19];
  const void* Wo    = d_in[20];
  const void* bo    = d_in[21];
  const void* ln1g  = d_in[22];
  const void* ln1b  = d_in[23];
  const void* W1    = d_in[24];
  const void* b1    = d_in[25];
  const void* W2    = d_in[26];
  const void* b2    = d_in[27];
  const void* ln2g  = d_in[28];
  const void* ln2b  = d_in[29];

  const size_t NHS = (size_t)NN * HHH;
  const size_t QKV3 = (size_t)3 * HHH * HHH;
  u16* ws = (u16*)d_ws;
  u16* socWT  = ws;
  u16* projWT = socWT + (size_t)DD * DD;
  u16* WqkvT  = projWT + (size_t)DD * HHH;
  u16* WoT    = WqkvT + (size_t)LLL * QKV3;
  u16* W1T    = WoT + (size_t)LLL * HHH * HHH;
  u16* W2T    = W1T + (size_t)LLL * HHH * PFF;
  u16* Hb     = W2T + (size_t)LLL * HHH * PFF;
  u16* P1     = Hb + NHS;
  u16* P2     = P1 + NHS;
  u16* P3     = P2 + NHS;
  int* flagp  = (int*)(P3 + NHS);
  u16* packb  = (u16*)(flagp + 4);
  u16* pet    = packb + 16384;                    // PE table [512,256]
  u16* FFMf   = pet + (size_t)SS * DD;            // full FFM [16384,2048] (if ws allows)
  size_t need_full = (size_t)(FFMf - ws + (size_t)NN * PFF) * 2;
  int fullff = (ws_size >= need_full);

  u16* X    = P1;
  u16* AGG  = P2;
  u16* SOCP = P3;
  u16* X2   = P2;
  u16* Ob   = (u16*)d_out;
  u16* FFMc = P2;    // chunked fallback: [8192,2048] spans P2+P3

  k_flag<<<1, 1, 0, stream>>>((const u32*)ln1g, flagp);

  dim3 tb(32, 8);
  k_transpose_all<<<dim3(192 + LLL * 3072), tb, 0, stream>>>(
      socW, projW, Wq, Wk, Wv, Wo, W1, W2,
      socWT, projWT, WqkvT, WoT, W1T, W2T, flagp);
  k_packb<<<dim3((512 + LLL * 4608 + 255) / 256), 256, 0, stream>>>(
      projb, bq, bk, bv, b1, bo, b2, packb, flagp);
  k_pe<<<SS, 256, 0, stream>>>(tB, pet, flagp);

  k_embed<<<NN, 256, 0, stream>>>(src, tiv, emb, tW, pet, X, flagp);
  k_agg<<<NN / 8, 256, 0, stream>>>(nidx, ncnt, X, AGG);
  k_gemm128<<<dim3(DD / 128, NN / 128), 256, 0, stream>>>(AGG, socWT, socb, 0, X, SOCP, DD, DD, 0, flagp);
  k_ln_soc<<<NN, 256, 0, stream>>>(SOCP, X, socg, socbe, ncnt, src, X2, d_out, flagp);
  // proj: [16384,256] @ [256,512] -> Hb
  k_gemm256<2><<<dim3(256), 512, 0, stream>>>(X2, projWT, packb, Hb, HHH, DD, 0, 4);

  for (int l = 0; l < LLL; ++l) {
    size_t oHH = (size_t)l * HHH * HHH, oHP = (size_t)l * HHH * PFF;
    u16* lb = packb + 512 + (size_t)l * 4608;
    // fused QKV: [16384,512] @ [512,1536] -> P1 (stride 1536). NBF=2, grid 768 = 2 blocks/CU.
    k_gemm256<2><<<dim3(768), 512, 0, stream>>>(Hb, WqkvT + (size_t)l * QKV3, lb, P1, 1536, HHH, 0, 12);
    k_attn_mfma<<<dim3(NHH, BB), 512, 0, stream>>>(P1, P1 + HHH, P1 + 2 * HHH, 3 * HHH, src, Ob);
    // Wo: [16384,512] @ [512,512] -> P1
    k_gemm256<2><<<dim3(256), 512, 0, stream>>>(Ob, WoT + oHH, lb + 3584, P1, HHH, HHH, 0, 4);
    k_ln_add<<<NN, 256, 0, stream>>>(Hb, P1, ln1g, l * HHH, ln1b, l * HHH, Hb, nullptr, flagp);
    if (fullff) {
      // FF1: [16384,512]@[512,2048] -> FFMf. NBF=2, grid 1024 = 2 blocks/CU, 2 full rounds.
      k_gemm256<2><<<dim3(1024), 512, 0, stream>>>(Hb, W1T + oHP, lb + 1536, FFMf, PFF, HHH, 1, 16);
      // FF2: [16384,2048]@[2048,512] -> P1 (grid 256)
      k_gemm256<2><<<dim3(256), 512, 0, stream>>>(FFMf, W2T + oHP, lb + 4096, P1, HHH, PFF, 0, 4);
    } else {
      for (int c = 0; c < 2; ++c) {
        const u16* Asrc = Hb + (size_t)c * 8192 * HHH;
        u16* Cdst = P1 + (size_t)c * 8192 * HHH;
        k_gemm256<2><<<dim3(512), 512, 0, stream>>>(Asrc, W1T + oHP, lb + 1536, FFMc, PFF, HHH, 1, 16);
        k_gemm256<2><<<dim3(128), 512, 0, stream>>>(FFMc, W2T + oHP, lb + 4096, Cdst, HHH, PFF, 0, 4);
      }
    }
    // last ln_add writes the output directly (dtype-converted); others write Hb
    void* dd = (l == LLL - 1) ? d_out : nullptr;
    k_ln_add<<<NN, 256, 0, stream>>>(Hb, P1, ln2g, l * HHH, ln2b, l * HHH, Hb, dd, flagp);
  }
}